// Round 10
// baseline (1127.402 us; speedup 1.0000x reference)
//
#include <hip/hip_runtime.h>
#include <hip/hip_bf16.h>
#include <math.h>

#define LAYERS 32
#define H      1024
#define H3     3072
#define NHEADS 16
#define HDIM   64
#define FF     2048
#define BATCH  2
#define SEQ    2048
#define EPSF   1e-6f

__device__ __forceinline__ float wredSum(float v) {
#pragma unroll
  for (int m = 32; m >= 1; m >>= 1) v += __shfl_xor(v, m, 64);
  return v;
}
__device__ __forceinline__ float wredMax(float v) {
#pragma unroll
  for (int m = 32; m >= 1; m >>= 1) v = fmaxf(v, __shfl_xor(v, m, 64));
  return v;
}
__device__ __forceinline__ float gelu_t(float x) {
  return 0.5f * x * (1.0f + tanhf(0.7978845608028654f * (x + 0.044715f * x * x * x)));
}
__device__ __forceinline__ float dot4(float4 a, float4 b) {
  return a.x * b.x + a.y * b.y + a.z * b.z + a.w * b.w;
}

// f32 agent-relaxed (MALL) ops — attP
__device__ __forceinline__ void ast(float* p, float v) {
  __hip_atomic_store(p, v, __ATOMIC_RELAXED, __HIP_MEMORY_SCOPE_AGENT);
}
__device__ __forceinline__ float ald(const float* p) {
  return __hip_atomic_load(p, __ATOMIC_RELAXED, __HIP_MEMORY_SCOPE_AGENT);
}
// packed batch-pair (8B) agent-relaxed ops — main data plane
union F2U { unsigned long long u; float f[2]; };
__device__ __forceinline__ void ast2(unsigned long long* p, float lo, float hi) {
  F2U x; x.f[0] = lo; x.f[1] = hi;
  __hip_atomic_store(p, x.u, __ATOMIC_RELAXED, __HIP_MEMORY_SCOPE_AGENT);
}
__device__ __forceinline__ float2 ald2(const unsigned long long* p) {
  F2U x; x.u = __hip_atomic_load(p, __ATOMIC_RELAXED, __HIP_MEMORY_SCOPE_AGENT);
  return make_float2(x.f[0], x.f[1]);
}

// ---- lean sync plane (r9-verified) ----------------------------------------
__device__ __forceinline__ void slot_mark(int* slots, int idx) {
  __syncthreads();
  if (threadIdx.x == 0)
    __hip_atomic_store(&slots[idx], 1, __ATOMIC_RELAXED, __HIP_MEMORY_SCOPE_AGENT);
}
__device__ __forceinline__ void leader_detect(int* slots, int n, int* flags) {
  for (int s = threadIdx.x; s < n; s += 256) {
    while (__hip_atomic_load(&slots[s], __ATOMIC_RELAXED, __HIP_MEMORY_SCOPE_AGENT) == 0)
      __builtin_amdgcn_s_sleep(2);
  }
  __syncthreads();
  if (threadIdx.x < 8)
    __hip_atomic_store(&flags[threadIdx.x * 16], 1, __ATOMIC_RELAXED, __HIP_MEMORY_SCOPE_AGENT);
  asm volatile("" ::: "memory");
}
__device__ __forceinline__ void flag_wait(int* flags, int bid) {
  if (threadIdx.x == 0) {
    while (__hip_atomic_load(&flags[(bid & 7) * 16], __ATOMIC_RELAXED, __HIP_MEMORY_SCOPE_AGENT) == 0)
      __builtin_amdgcn_s_sleep(8);
  }
  __syncthreads();
  asm volatile("" ::: "memory");
}

union SH2 {
  struct { float xe[2048]; float red[8]; } ns;
  struct { float ys[2048]; float sml[512]; } mx;
  struct { float hs[4096]; } w2;
  struct { float q[64]; float k[64]; float v[64]; float eg[256]; float redA[4]; float osum[4][64]; } att;
};

// per-layer slot layout (4096 ints): P[0,768) attn[1024,1280) mix[1536,1792)
// W1[2048,2560) W2[2560,2816); flags F0@3072(->attn) F1@3200(->mix)
// F2@3328(->W1) F3@3456(->W2) F4@3584(->P of this layer, from prev W2)
// uniform 2048 blocks/layer: P 768 | attn 256 (idle if !ATT) | mix 256 | W1 512 | W2 256
__global__ __launch_bounds__(256, 8) void mega(
    const float* __restrict__ x0, const int* __restrict__ posp,
    const float* __restrict__ n1, const float* __restrict__ n2,
    const float* __restrict__ pW, const float* __restrict__ pb,
    const float* __restrict__ oW, const float* __restrict__ ob,
    const float* __restrict__ W1, const float* __restrict__ W2,
    const float* __restrict__ sfc, const float* __restrict__ sfd,
    const float* __restrict__ mix0, const float* __restrict__ mix1,
    const float* __restrict__ kc, const float* __restrict__ vc,
    const float* __restrict__ cosT, const float* __restrict__ sinT,
    unsigned long long* __restrict__ z2, float* __restrict__ attP,
    unsigned long long* __restrict__ xM2, unsigned long long* __restrict__ h2,
    unsigned long long* __restrict__ xqA, unsigned long long* __restrict__ xqB,
    int* __restrict__ bar, float* __restrict__ dout)
{
  __shared__ SH2 sh;
  int bid = blockIdx.x, tid = threadIdx.x, lane = tid & 63, w = tid >> 6;
  int layer = bid >> 11, local = bid & 2047;
  int r7 = layer % 7;
  int kind = (r7 == 3) ? 3 : ((r7 == 0 || r7 == 4) ? 0 : ((r7 == 1 || r7 == 5) ? 1 : 2));
  int* barL = bar + layer * 4096;
  unsigned long long* xr = (layer & 1) ? xqA : xqB;   // read buf (prev layer's out)
  unsigned long long* xw = (layer & 1) ? xqB : xqA;   // write buf

  if (local < 768) {
    // ================= P: rmsnorm(x) + proj GEMV -> z2 =================
    int r = local * 4 + w;
    const float4* rowp = (const float4*)(pW + (size_t)layer * H3 * H + (size_t)r * H);
    float4 wv0 = rowp[lane], wv1 = rowp[lane + 64],
           wv2 = rowp[lane + 128], wv3 = rowp[lane + 192];
    float4 nv = ((const float4*)(n1 + (size_t)layer * H))[tid];
    if (layer > 0) {
      if (local == 0) leader_detect(bar + (layer - 1) * 4096 + 2560, 256, barL + 3584);
      else            flag_wait(barL + 3584, local);
    }
    float ss0 = 0.f, ss1 = 0.f;
    if (layer == 0) {
      float4 xv0 = ((const float4*)x0)[tid];
      float4 xv1 = ((const float4*)x0)[tid + 256];
      ss0 = dot4(xv0, xv0); ss1 = dot4(xv1, xv1);
      ((float4*)sh.ns.xe)[tid]       = make_float4(xv0.x * nv.x, xv0.y * nv.y, xv0.z * nv.z, xv0.w * nv.w);
      ((float4*)sh.ns.xe)[tid + 256] = make_float4(xv1.x * nv.x, xv1.y * nv.y, xv1.z * nv.z, xv1.w * nv.w);
    } else {
      float nn[4] = {nv.x, nv.y, nv.z, nv.w};
#pragma unroll
      for (int j = 0; j < 4; j++) {
        float2 v = ald2(&xr[4 * tid + j]);
        ss0 += v.x * v.x; ss1 += v.y * v.y;
        sh.ns.xe[4 * tid + j] = v.x * nn[j];
        sh.ns.xe[1024 + 4 * tid + j] = v.y * nn[j];
      }
    }
    ss0 = wredSum(ss0); ss1 = wredSum(ss1);
    if (lane == 0) { sh.ns.red[w] = ss0; sh.ns.red[4 + w] = ss1; }
    __syncthreads();
    float s0 = rsqrtf((sh.ns.red[0] + sh.ns.red[1] + sh.ns.red[2] + sh.ns.red[3]) * (1.0f / H) + EPSF);
    float s1 = rsqrtf((sh.ns.red[4] + sh.ns.red[5] + sh.ns.red[6] + sh.ns.red[7]) * (1.0f / H) + EPSF);
    const float4* x4 = (const float4*)sh.ns.xe;
    float a0 = dot4(wv0, x4[lane])       + dot4(wv1, x4[lane + 64])
             + dot4(wv2, x4[lane + 128]) + dot4(wv3, x4[lane + 192]);
    float a1 = dot4(wv0, x4[lane + 256]) + dot4(wv1, x4[lane + 320])
             + dot4(wv2, x4[lane + 384]) + dot4(wv3, x4[lane + 448]);
    a0 = wredSum(a0); a1 = wredSum(a1);
    if (lane == 0) {
      float b0 = pb[(size_t)layer * H3 + r];
      ast2(&z2[r], a0 * s0 + b0, a1 * s1 + b0);
    }
    slot_mark(barL, local);

  } else if (local < 1024) {
    // ================= attn: flash-decode partials =====================
    if (kind != 3) return;
    int mb = local - 768;
    int sp = mb & 7, n = (mb >> 3) & 15, b = mb >> 7;
    int att = layer / 7;
    const float* kcL = kc + (size_t)att * BATCH * SEQ * NHEADS * HDIM;
    const float* vcL = vc + (size_t)att * BATCH * SEQ * NHEADS * HDIM;
    int pos = *posp;
    if (mb == 0) leader_detect(barL, 768, barL + 3072);
    else         flag_wait(barL + 3072, local);
    if (tid < 64) {
      int d = tid, j = d & 31;
      float cs = cosT[pos * 32 + j], sn = sinT[pos * 32 + j];
      float2 zq  = ald2(&z2[n * 64 + d]);
      float2 zqo = ald2(&z2[n * 64 + ((d + 32) & 63)]);
      float2 zk  = ald2(&z2[1024 + n * 64 + d]);
      float2 zko = ald2(&z2[1024 + n * 64 + ((d + 32) & 63)]);
      float2 zv  = ald2(&z2[2048 + n * 64 + d]);
      float qv = b ? zq.y : zq.x,  qo = b ? zqo.y : zqo.x;
      float kv = b ? zk.y : zk.x,  ko = b ? zko.y : zko.x;
      sh.att.q[d] = ((d < 32) ? (qv * cs - qo * sn) : (qv * cs + qo * sn)) * 0.125f;
      sh.att.k[d] = (d < 32) ? (kv * cs - ko * sn) : (kv * cs + ko * sn);
      sh.att.v[d] = b ? zv.y : zv.x;
    }
    __syncthreads();
    int s = sp * 256 + tid;
    float logit = -1e30f;
    if (s <= pos) {
      const float4* k4 = (s == pos) ? (const float4*)sh.att.k
                                    : (const float4*)(kcL + (((size_t)b * SEQ + s) * NHEADS + n) * HDIM);
      const float4* q4 = (const float4*)sh.att.q;
      float acc = 0.f;
#pragma unroll
      for (int j = 0; j < 16; j++) acc += dot4(k4[j], q4[j]);
      logit = acc;
    }
    float m = wredMax(logit);
    if (lane == 0) sh.att.redA[w] = m;
    __syncthreads();
    m = fmaxf(fmaxf(sh.att.redA[0], sh.att.redA[1]), fmaxf(sh.att.redA[2], sh.att.redA[3]));
    float e = (s <= pos) ? expf(logit - m) : 0.f;
    sh.att.eg[tid] = e;
    float ps = wredSum(e);
    __syncthreads();
    if (lane == 0) sh.att.redA[w] = ps;
    __syncthreads();
    float lsum = sh.att.redA[0] + sh.att.redA[1] + sh.att.redA[2] + sh.att.redA[3];
    int dgrp = lane & 15, srow = lane >> 4;
    float4 acc = make_float4(0.f, 0.f, 0.f, 0.f);
#pragma unroll 4
    for (int it = 0; it < 16; it++) {
      int sl = w * 64 + it * 4;
      if (sp * 256 + sl > pos) break;            // uniform within wave
      int sli = sl + srow;
      int ss2 = sp * 256 + sli;
      float ev = sh.att.eg[sli];
      const float4* v4 = (ss2 == pos) ? (const float4*)sh.att.v
                                      : (const float4*)(vcL + (((size_t)b * SEQ + ss2) * NHEADS + n) * HDIM);
      float4 vv = v4[dgrp];
      acc.x += ev * vv.x; acc.y += ev * vv.y; acc.z += ev * vv.z; acc.w += ev * vv.w;
    }
#pragma unroll
    for (int mm = 16; mm <= 32; mm <<= 1) {
      acc.x += __shfl_xor(acc.x, mm, 64);
      acc.y += __shfl_xor(acc.y, mm, 64);
      acc.z += __shfl_xor(acc.z, mm, 64);
      acc.w += __shfl_xor(acc.w, mm, 64);
    }
    if (srow == 0) ((float4*)sh.att.osum[w])[dgrp] = acc;
    __syncthreads();
    float* Pp = attP + (size_t)((sp * BATCH + b) * NHEADS + n) * 66;
    if (tid < 64) ast(&Pp[tid], sh.att.osum[0][tid] + sh.att.osum[1][tid] + sh.att.osum[2][tid] + sh.att.osum[3][tid]);
    if (tid == 64) ast(&Pp[64], m);
    if (tid == 65) ast(&Pp[65], lsum);
    slot_mark(barL + 1024, mb);

  } else if (local < 1280) {
    // ================= mix: y -> oW GEMV + bias + residual -> xM2 ======
    int mb = local - 1024;
    int r = mb * 4 + w;
    const float4* rowp = (const float4*)(oW + (size_t)layer * H * H + (size_t)r * H);
    float4 wv0 = rowp[lane], wv1 = rowp[lane + 64],
           wv2 = rowp[lane + 128], wv3 = rowp[lane + 192];
    const float* sfcL = sfc + (size_t)layer * H3;
    const float* sfdL = sfd + (size_t)layer * 2 * H3;
    const float* mix0L = mix0 + (size_t)layer * 2 * H;
    const float* mix1L = mix1 + (size_t)layer * H;
    if (kind != 3) {
      if (mb == 0) leader_detect(barL, 768, barL + 3200);
      else         flag_wait(barL + 3200, local);
#pragma unroll
      for (int k = 0; k < 4; k++) {
        int c = tid + k * 256;
        int n = c >> 6, d = c & 63;
        int base = n * 192 + d;
        float2 za = ald2(&z2[base]);
        float2 zb = ald2(&z2[base + 64]);
        float2 zc = ald2(&z2[base + 128]);
        float x2a = sfcL[base] * za.x + sfdL[base];
        float x2b = sfcL[base] * za.y + sfdL[H3 + base];
        float x1a = sfcL[base + 64] * zb.x + sfdL[base + 64];
        float x1b = sfcL[base + 64] * zb.y + sfdL[H3 + base + 64];
        float va  = sfcL[base + 128] * zc.x + sfdL[base + 128];
        float vb  = sfcL[base + 128] * zc.y + sfdL[H3 + base + 128];
        sh.mx.ys[c]        = (mix1L[c] * (x1a * va) + mix0L[c]) * x2a;
        sh.mx.ys[1024 + c] = (mix1L[c] * (x1b * vb) + mix0L[H + c]) * x2b;
      }
    } else {
      if (mb == 0) leader_detect(barL + 1024, 256, barL + 3200);
      else         flag_wait(barL + 3200, local);
      if (tid < 256) {
        int sp = tid & 7, n = (tid >> 3) & 15, b = tid >> 7;
        const float* Pp = attP + (size_t)((sp * BATCH + b) * NHEADS + n) * 66;
        sh.mx.sml[tid * 2] = ald(&Pp[64]);
        sh.mx.sml[tid * 2 + 1] = ald(&Pp[65]);
      }
      __syncthreads();
#pragma unroll
      for (int it = 0; it < 8; it++) {
        int e = tid + it * 256;
        int b = e >> 10, c = e & 1023;
        int n = c >> 6, d = c & 63;
        float M = -1e30f;
#pragma unroll
        for (int sp = 0; sp < 8; sp++) M = fmaxf(M, sh.mx.sml[(((b << 4) | n) * 8 + sp) * 2]);
        float Ls = 0.f, num = 0.f;
#pragma unroll
        for (int sp = 0; sp < 8; sp++) {
          float Msp = sh.mx.sml[(((b << 4) | n) * 8 + sp) * 2];
          float Lsp = sh.mx.sml[(((b << 4) | n) * 8 + sp) * 2 + 1];
          float wgt = expf(Msp - M);
          Ls += wgt * Lsp;
          num += wgt * ald(&attP[(size_t)((sp * BATCH + b) * NHEADS + n) * 66 + d]);
        }
        sh.mx.ys[e] = num / Ls;
      }
    }
    __syncthreads();
    const float4* y4 = (const float4*)sh.mx.ys;
    float a0 = dot4(wv0, y4[lane])       + dot4(wv1, y4[lane + 64])
             + dot4(wv2, y4[lane + 128]) + dot4(wv3, y4[lane + 192]);
    float a1 = dot4(wv0, y4[lane + 256]) + dot4(wv1, y4[lane + 320])
             + dot4(wv2, y4[lane + 384]) + dot4(wv3, y4[lane + 448]);
    a0 = wredSum(a0); a1 = wredSum(a1);
    if (lane == 0) {
      float obv = ob[(size_t)layer * H + r];
      float xi0, xi1;
      if (layer == 0) { xi0 = x0[r]; xi1 = x0[H + r]; }
      else { float2 t = ald2(&xr[r]); xi0 = t.x; xi1 = t.y; }
      ast2(&xM2[r], a0 + obv + xi0, a1 + obv + xi1);
    }
    slot_mark(barL + 1536, mb);

  } else if (local < 1792) {
    // ================= W1: rmsnorm(xM2) + W1 GEMV + gelu -> h2 =========
    int wb = local - 1280;
    int r = wb * 4 + w;
    const float4* rowp = (const float4*)(W1 + (size_t)layer * FF * H + (size_t)r * H);
    float4 wv0 = rowp[lane], wv1 = rowp[lane + 64],
           wv2 = rowp[lane + 128], wv3 = rowp[lane + 192];
    if (wb == 0) leader_detect(barL + 1536, 256, barL + 3328);
    else         flag_wait(barL + 3328, local);
    float ss0 = 0.f, ss1 = 0.f;
#pragma unroll
    for (int k = 0; k < 4; k++) {
      int c = tid + k * 256;
      float2 xv = ald2(&xM2[c]);
      ss0 += xv.x * xv.x; ss1 += xv.y * xv.y;
      float nvj = n2[(size_t)layer * H + c];
      sh.ns.xe[c] = xv.x * nvj;
      sh.ns.xe[1024 + c] = xv.y * nvj;
    }
    ss0 = wredSum(ss0); ss1 = wredSum(ss1);
    if (lane == 0) { sh.ns.red[w] = ss0; sh.ns.red[4 + w] = ss1; }
    __syncthreads();
    float s0 = rsqrtf((sh.ns.red[0] + sh.ns.red[1] + sh.ns.red[2] + sh.ns.red[3]) * (1.0f / H) + EPSF);
    float s1 = rsqrtf((sh.ns.red[4] + sh.ns.red[5] + sh.ns.red[6] + sh.ns.red[7]) * (1.0f / H) + EPSF);
    const float4* x4 = (const float4*)sh.ns.xe;
    float a0 = dot4(wv0, x4[lane])       + dot4(wv1, x4[lane + 64])
             + dot4(wv2, x4[lane + 128]) + dot4(wv3, x4[lane + 192]);
    float a1 = dot4(wv0, x4[lane + 256]) + dot4(wv1, x4[lane + 320])
             + dot4(wv2, x4[lane + 384]) + dot4(wv3, x4[lane + 448]);
    a0 = wredSum(a0); a1 = wredSum(a1);
    if (lane == 0) ast2(&h2[r], gelu_t(a0 * s0), gelu_t(a1 * s1));
    slot_mark(barL + 2048, wb);

  } else {
    // ================= W2: W2 GEMV + residual -> x_out =================
    int vb = local - 1792;
    int r = vb * 4 + w;
    const float4* rowp = (const float4*)(W2 + (size_t)layer * H * FF + (size_t)r * FF);
    float4 wv[8];
#pragma unroll
    for (int j = 0; j < 8; j++) wv[j] = rowp[lane + 64 * j];
    if (vb == 0) leader_detect(barL + 2048, 512, barL + 3456);
    else         flag_wait(barL + 3456, local);
#pragma unroll
    for (int it = 0; it < 8; it++) {
      int e = tid + it * 256;
      float2 hv = ald2(&h2[e]);
      sh.w2.hs[e] = hv.x;
      sh.w2.hs[2048 + e] = hv.y;
    }
    __syncthreads();
    const float4* h4 = (const float4*)sh.w2.hs;
    float a0 = 0.f, a1 = 0.f;
#pragma unroll
    for (int j = 0; j < 8; j++) {
      a0 += dot4(wv[j], h4[lane + 64 * j]);
      a1 += dot4(wv[j], h4[lane + 64 * j + 512]);
    }
    a0 = wredSum(a0); a1 = wredSum(a1);
    if (lane == 0) {
      float2 xm = ald2(&xM2[r]);
      if (layer == LAYERS - 1) {
        dout[r]     = a0 + xm.x;
        dout[H + r] = a1 + xm.y;
      } else {
        ast2(&xw[r], a0 + xm.x, a1 + xm.y);
      }
    }
    slot_mark(barL + 2560, vb);
  }
}

// ---------------------------------------------------------------------------
// prep: hoist state-linear terms (r1-verified) + zero sync plane
// ---------------------------------------------------------------------------
__global__ __launch_bounds__(256) void prep_kernel(
    const float* __restrict__ sf_w, const float* __restrict__ sf_b,
    const float* __restrict__ fir_state,
    const float* __restrict__ hcs_h, const float* __restrict__ hcs_D, const float* __restrict__ hcs_state,
    const float* __restrict__ hcm_h, const float* __restrict__ hcm_D, const float* __restrict__ hcm_state,
    const float* __restrict__ lp, const float* __restrict__ resd, const float* __restrict__ hcl_D,
    const float* __restrict__ iir,
    unsigned long long kbits,
    float* __restrict__ sfd, float* __restrict__ sfc,
    float* __restrict__ mix0, float* __restrict__ mix1, int* __restrict__ bar)
{
  int blk = blockIdx.x, tid = threadIdx.x;
  if (blk < 768) {
    int idx = blk * 256 + tid;
    int i = idx / (BATCH * H3);
    int r = idx % (BATCH * H3);
    int b = r / H3, ch = r % H3;
    const float* fs = fir_state + ((size_t)(i * BATCH + b) * H3 + ch) * 2;
    const float* sw = sf_w + ((size_t)i * H3 + ch) * 3;
    sfd[idx] = fs[0] * sw[0] + fs[1] * sw[1] + sf_b[i * H3 + ch];
    if (b == 0) sfc[i * H3 + ch] = sw[2];
  } else if (blk < 1024) {
    int idx = (blk - 768) * 256 + tid;
    int i = idx >> 11;
    int r = idx & 2047;
    int b = r >> 10, c = r & 1023;
    int kind = (int)((kbits >> (2 * i)) & 3ull);
    if (kind == 0) {
      const float* st = hcs_state + ((size_t)(i * BATCH + b) * H + c) * 6;
      const float* hh = hcs_h + ((size_t)i * H + c) * 7;
      float acc = 0.f;
#pragma unroll
      for (int k = 0; k < 6; k++) acc += st[k] * hh[k];
      mix0[idx] = acc + hcs_D[i * H + c];
      if (b == 0) mix1[i * H + c] = hh[6];
    } else if (kind == 2) {
      const float* ii = iir + ((size_t)(i * BATCH + b) * H + c) * 16;
      const float* lpp = lp + ((size_t)i * H + c) * 16;
      const float* rs = resd + ((size_t)i * H + c) * 16;
      float acc = 0.f, rsum = 0.f;
#pragma unroll
      for (int k = 0; k < 16; k++) { float rv = rs[k]; acc += rv * expf(lpp[k]) * ii[k]; rsum += rv; }
      mix0[idx] = acc;
      if (b == 0) mix1[i * H + c] = rsum + hcl_D[i * H + c];
    }
  } else if (blk < 5632) {
    int w = tid >> 6, lane = tid & 63;
    int widx = (blk - 1024) * 4 + w;
    if (widx < 9 * BATCH * H) {
      int li = widx >> 11;
      int r = widx & 2047;
      int b = r >> 10, c = r & 1023;
      int i = (li >> 1) * 7 + ((li & 1) ? 5 : 1);  // HCM layers 1,5,8,12,15,19,22,26,29
      const float* st = hcm_state + ((size_t)(i * BATCH + b) * H + c) * 127;
      const float* hh = hcm_h + ((size_t)i * H + c) * 128;
      float acc = 0.f;
      int k = lane;
      if (k < 127) acc += st[k] * hh[127 - k];
      k = lane + 64;
      if (k < 127) acc += st[k] * hh[127 - k];
      acc = wredSum(acc);
      if (lane == 0) {
        mix0[(i * BATCH + b) * H + c] = acc;
        if (b == 0) mix1[i * H + c] = hh[0] + hcm_D[i * H + c];
      }
    }
  } else {
    int idx = (blk - 5632) * 256 + tid;
    if (idx < LAYERS * 4096) bar[idx] = 0;
  }
}

// ---------------------------------------------------------------------------
extern "C" void kernel_launch(void* const* d_in, const int* in_sizes, int n_in,
                              void* d_out, int out_size, void* d_ws, size_t ws_size,
                              hipStream_t stream) {
  (void)in_sizes; (void)n_in; (void)out_size; (void)ws_size;
  const float* x0    = (const float*)d_in[0];
  const int*   posp  = (const int*)d_in[1];
  const float* n1    = (const float*)d_in[2];
  const float* n2    = (const float*)d_in[3];
  const float* pW    = (const float*)d_in[4];
  const float* pb    = (const float*)d_in[5];
  const float* oW    = (const float*)d_in[6];
  const float* ob    = (const float*)d_in[7];
  const float* W1    = (const float*)d_in[8];
  const float* W2    = (const float*)d_in[9];
  const float* sfw   = (const float*)d_in[10];
  const float* sfb   = (const float*)d_in[11];
  const float* hcs_h = (const float*)d_in[12];
  const float* hcs_D = (const float*)d_in[13];
  const float* hcm_h = (const float*)d_in[14];
  const float* hcm_D = (const float*)d_in[15];
  const float* lp    = (const float*)d_in[16];
  const float* resd  = (const float*)d_in[17];
  const float* hclD  = (const float*)d_in[18];
  const float* fir   = (const float*)d_in[19];
  const float* hcsS  = (const float*)d_in[20];
  const float* hcmS  = (const float*)d_in[21];
  const float* iir   = (const float*)d_in[22];
  const float* kc    = (const float*)d_in[23];
  const float* vc    = (const float*)d_in[24];
  const float* cosT  = (const float*)d_in[25];
  const float* sinT  = (const float*)d_in[26];

  float* ws    = (float*)d_ws;
  unsigned long long* xqA = (unsigned long long*)ws;            // 1024 ull
  unsigned long long* xqB = (unsigned long long*)(ws + 2048);   // 1024 ull
  unsigned long long* xM2 = (unsigned long long*)(ws + 4096);   // 1024 ull
  unsigned long long* z2  = (unsigned long long*)(ws + 6144);   // 3072 ull
  unsigned long long* h2  = (unsigned long long*)(ws + 12288);  // 2048 ull
  float* attP  = ws + 16384;         // 16896
  float* sfd   = ws + 33280;         // 196608
  float* sfc   = ws + 229888;        // 98304
  float* mix0  = ws + 328192;        // 65536
  float* mix1  = ws + 393728;        // 32768
  int*   bar   = (int*)(ws + 426496); // 32*4096 ints

  static const int KIND[LAYERS] = {0,1,2,3,0,1,2,0,1,2,3,0,1,2,0,1,2,3,0,1,2,0,1,2,3,0,1,2,0,1,2,3};
  unsigned long long kbits = 0ull;
  for (int i = 0; i < LAYERS; i++) kbits |= ((unsigned long long)KIND[i]) << (2 * i);

  prep_kernel<<<6144, 256, 0, stream>>>(sfw, sfb, fir, hcs_h, hcs_D, hcsS,
      hcm_h, hcm_D, hcmS, lp, resd, hclD, iir, kbits, sfd, sfc, mix0, mix1, bar);

  mega<<<LAYERS * 2048, 256, 0, stream>>>(
      x0, posp, n1, n2, pW, pb, oW, ob, W1, W2,
      sfc, sfd, mix0, mix1, kc, vc, cosT, sinT,
      z2, attP, xM2, h2, xqA, xqB, bar, (float*)d_out);
}

// Round 11
// 886.698 us; speedup vs baseline: 1.2715x; 1.2715x over previous
//
#include <hip/hip_runtime.h>
#include <hip/hip_bf16.h>
#include <math.h>

#define LAYERS 32
#define H      1024
#define H3     3072
#define NHEADS 16
#define HDIM   64
#define FF     2048
#define BATCH  2
#define SEQ    2048
#define EPSF   1e-6f
#define LINE   128

__device__ __forceinline__ float wredSum(float v) {
#pragma unroll
  for (int m = 32; m >= 1; m >>= 1) v += __shfl_xor(v, m, 64);
  return v;
}
__device__ __forceinline__ float wredMax(float v) {
#pragma unroll
  for (int m = 32; m >= 1; m >>= 1) v = fmaxf(v, __shfl_xor(v, m, 64));
  return v;
}
__device__ __forceinline__ float gelu_t(float x) {
  return 0.5f * x * (1.0f + tanhf(0.7978845608028654f * (x + 0.044715f * x * x * x)));
}
__device__ __forceinline__ float dot4(float4 a, float4 b) {
  return a.x * b.x + a.y * b.y + a.z * b.z + a.w * b.w;
}

// agent-relaxed (MALL-coherent) data plane
__device__ __forceinline__ void ast(float* p, float v) {
  __hip_atomic_store(p, v, __ATOMIC_RELAXED, __HIP_MEMORY_SCOPE_AGENT);
}
__device__ __forceinline__ float ald(const float* p) {
  return __hip_atomic_load(p, __ATOMIC_RELAXED, __HIP_MEMORY_SCOPE_AGENT);
}
union F2U { unsigned long long u; float f[2]; };
__device__ __forceinline__ void ast2(unsigned long long* p, float lo, float hi) {
  F2U x; x.f[0] = lo; x.f[1] = hi;
  __hip_atomic_store(p, x.u, __ATOMIC_RELAXED, __HIP_MEMORY_SCOPE_AGENT);
}
__device__ __forceinline__ float2 ald2(const unsigned long long* p) {
  F2U x; x.u = __hip_atomic_load(p, __ATOMIC_RELAXED, __HIP_MEMORY_SCOPE_AGENT);
  return make_float2(x.f[0], x.f[1]);
}

// ---- direct-scan sync plane: 64 lines x 128B; producer idx -> line idx&63,
// byte idx>>6; waiters scan all 64 lines with one parallel wave burst --------
__device__ __forceinline__ void plane_mark(unsigned char* plane, int idx) {
  __syncthreads();  // drain this block's data stores first
  if (threadIdx.x == 0)
    __hip_atomic_store(plane + (size_t)(idx & 63) * LINE + (idx >> 6),
                       (unsigned char)0xFF, __ATOMIC_RELAXED, __HIP_MEMORY_SCOPE_AGENT);
}
template<int NDW>   // dwords per line to verify: 1 (256 prod), 2 (512), 3 (768)
__device__ __forceinline__ void plane_wait(const unsigned char* plane) {
  if (threadIdx.x < 64) {
    const unsigned int* lp = (const unsigned int*)(plane + (size_t)threadIdx.x * LINE);
    for (;;) {
      bool ok = __hip_atomic_load(lp, __ATOMIC_RELAXED, __HIP_MEMORY_SCOPE_AGENT) == 0xFFFFFFFFu;
      if (NDW > 1) ok &= __hip_atomic_load(lp + 1, __ATOMIC_RELAXED, __HIP_MEMORY_SCOPE_AGENT) == 0xFFFFFFFFu;
      if (NDW > 2) ok &= __hip_atomic_load(lp + 2, __ATOMIC_RELAXED, __HIP_MEMORY_SCOPE_AGENT) == 0xFFFFFFFFu;
      if (__all(ok)) break;
      __builtin_amdgcn_s_sleep(4);
    }
  }
  __syncthreads();
  asm volatile("" ::: "memory");
}

union SH2 {
  struct { float xe[2048]; float red[8]; } ns;
  struct { float ys[2048]; float sml[512]; } mx;
  struct { float hs[4096]; } w2;
  struct { float q[64]; float k[64]; float v[64]; float eg[256]; float redA[4]; float osum[4][64]; } att;
};

// planes per layer (32KB): P @ +0, attn @ +8K, mix @ +16K, W1 @ +24K
// non-ATT grid 1280: P-triple 256 | mix 256 | W1 512 | W2 256
// ATT    grid 2048: P-flat 768 | attn 256 | mix 256 | W1 512 | W2 256
__global__ __launch_bounds__(256, 4) void layer_k(
    int kind, int att,
    const float* __restrict__ xin, float* __restrict__ xout,
    const float* __restrict__ n1L, const float* __restrict__ n2L,
    const float* __restrict__ pWL, const float* __restrict__ pbL,
    const float* __restrict__ oWL, const float* __restrict__ obL,
    const float* __restrict__ W1L, const float* __restrict__ W2L,
    const float* __restrict__ sfcL, const float* __restrict__ sfdL,
    const float* __restrict__ mix0L, const float* __restrict__ mix1L,
    const float* __restrict__ kc, const float* __restrict__ vc,
    const int* __restrict__ posp,
    const float* __restrict__ cosT, const float* __restrict__ sinT,
    unsigned long long* __restrict__ z2, unsigned long long* __restrict__ y2,
    float* __restrict__ attP,
    unsigned long long* __restrict__ xM2, unsigned long long* __restrict__ h2,
    unsigned char* __restrict__ plane)
{
  __shared__ SH2 sh;
  int local = blockIdx.x, tid = threadIdx.x, lane = tid & 63, w = tid >> 6;
  unsigned char* plP   = plane;
  unsigned char* plAtt = plane + 8192;
  unsigned char* plMix = plane + 16384;
  unsigned char* plW1  = plane + 24576;
  int isAtt = (kind == 3);
  int mixBase = isAtt ? 1024 : 256;
  int w1Base  = mixBase + 256;
  int w2Base  = w1Base + 512;

  if (!isAtt && local < 256) {
    // ========== P-triple: norm + 3 proj rows/wave + mixer -> y2 ==========
    int c0 = local * 4 + w;                 // channel 0..1023
    int n = c0 >> 6, d = c0 & 63;
    int R0 = n * 192 + d, R1 = R0 + 64, R2 = R0 + 128;
    const float4* r0p = (const float4*)(pWL + (size_t)R0 * H);
    const float4* r1p = (const float4*)(pWL + (size_t)R1 * H);
    const float4* r2p = (const float4*)(pWL + (size_t)R2 * H);
    float4 w0[4], w1v[4], w2v[4];
#pragma unroll
    for (int k = 0; k < 4; k++) { w0[k] = r0p[lane + 64 * k]; w1v[k] = r1p[lane + 64 * k]; w2v[k] = r2p[lane + 64 * k]; }
    // mixer scalars (uniform per wave) — issued early, consumed at epilogue
    float pb0 = pbL[R0], pb1 = pbL[R1], pb2 = pbL[R2];
    float sc0 = sfcL[R0], sc1 = sfcL[R1], sc2 = sfcL[R2];
    float sd00 = sfdL[R0], sd10 = sfdL[H3 + R0];
    float sd01 = sfdL[R1], sd11 = sfdL[H3 + R1];
    float sd02 = sfdL[R2], sd12 = sfdL[H3 + R2];
    float m0a = mix0L[c0], m0b = mix0L[H + c0], m1c = mix1L[c0];

    float4 xv0 = ((const float4*)xin)[tid];
    float4 xv1 = ((const float4*)xin)[tid + 256];
    float4 nv  = ((const float4*)n1L)[tid];
    float ss0 = dot4(xv0, xv0), ss1 = dot4(xv1, xv1);
    ((float4*)sh.ns.xe)[tid]       = make_float4(xv0.x * nv.x, xv0.y * nv.y, xv0.z * nv.z, xv0.w * nv.w);
    ((float4*)sh.ns.xe)[tid + 256] = make_float4(xv1.x * nv.x, xv1.y * nv.y, xv1.z * nv.z, xv1.w * nv.w);
    ss0 = wredSum(ss0); ss1 = wredSum(ss1);
    if (lane == 0) { sh.ns.red[w] = ss0; sh.ns.red[4 + w] = ss1; }
    __syncthreads();
    float s0 = rsqrtf((sh.ns.red[0] + sh.ns.red[1] + sh.ns.red[2] + sh.ns.red[3]) * (1.0f / H) + EPSF);
    float s1 = rsqrtf((sh.ns.red[4] + sh.ns.red[5] + sh.ns.red[6] + sh.ns.red[7]) * (1.0f / H) + EPSF);
    const float4* x4 = (const float4*)sh.ns.xe;
    float a00 = 0.f, a01 = 0.f, a10 = 0.f, a11 = 0.f, a20 = 0.f, a21 = 0.f;
#pragma unroll
    for (int k = 0; k < 4; k++) {
      float4 h0 = x4[lane + 64 * k], h1 = x4[lane + 64 * k + 256];
      a00 += dot4(w0[k], h0);  a01 += dot4(w0[k], h1);
      a10 += dot4(w1v[k], h0); a11 += dot4(w1v[k], h1);
      a20 += dot4(w2v[k], h0); a21 += dot4(w2v[k], h1);
    }
    a00 = wredSum(a00); a01 = wredSum(a01);
    a10 = wredSum(a10); a11 = wredSum(a11);
    a20 = wredSum(a20); a21 = wredSum(a21);
    if (lane == 0) {
      float x2a = sc0 * (a00 * s0 + pb0) + sd00;
      float x2b = sc0 * (a01 * s1 + pb0) + sd10;
      float x1a = sc1 * (a10 * s0 + pb1) + sd01;
      float x1b = sc1 * (a11 * s1 + pb1) + sd11;
      float va  = sc2 * (a20 * s0 + pb2) + sd02;
      float vb  = sc2 * (a21 * s1 + pb2) + sd12;
      ast2(&y2[c0], (m1c * (x1a * va) + m0a) * x2a, (m1c * (x1b * vb) + m0b) * x2b);
    }
    plane_mark(plP, local);

  } else if (isAtt && local < 768) {
    // ========== P-flat (ATT): norm + proj GEMV -> z2 ==========
    int r = local * 4 + w;
    const float4* rowp = (const float4*)(pWL + (size_t)r * H);
    float4 wv0 = rowp[lane], wv1 = rowp[lane + 64],
           wv2 = rowp[lane + 128], wv3 = rowp[lane + 192];
    float4 xv0 = ((const float4*)xin)[tid];
    float4 xv1 = ((const float4*)xin)[tid + 256];
    float4 nv  = ((const float4*)n1L)[tid];
    float ss0 = dot4(xv0, xv0), ss1 = dot4(xv1, xv1);
    ((float4*)sh.ns.xe)[tid]       = make_float4(xv0.x * nv.x, xv0.y * nv.y, xv0.z * nv.z, xv0.w * nv.w);
    ((float4*)sh.ns.xe)[tid + 256] = make_float4(xv1.x * nv.x, xv1.y * nv.y, xv1.z * nv.z, xv1.w * nv.w);
    ss0 = wredSum(ss0); ss1 = wredSum(ss1);
    if (lane == 0) { sh.ns.red[w] = ss0; sh.ns.red[4 + w] = ss1; }
    __syncthreads();
    float s0 = rsqrtf((sh.ns.red[0] + sh.ns.red[1] + sh.ns.red[2] + sh.ns.red[3]) * (1.0f / H) + EPSF);
    float s1 = rsqrtf((sh.ns.red[4] + sh.ns.red[5] + sh.ns.red[6] + sh.ns.red[7]) * (1.0f / H) + EPSF);
    const float4* x4 = (const float4*)sh.ns.xe;
    float a0 = dot4(wv0, x4[lane])       + dot4(wv1, x4[lane + 64])
             + dot4(wv2, x4[lane + 128]) + dot4(wv3, x4[lane + 192]);
    float a1 = dot4(wv0, x4[lane + 256]) + dot4(wv1, x4[lane + 320])
             + dot4(wv2, x4[lane + 384]) + dot4(wv3, x4[lane + 448]);
    a0 = wredSum(a0); a1 = wredSum(a1);
    if (lane == 0) {
      float b0 = pbL[r];
      ast2(&z2[r], a0 * s0 + b0, a1 * s1 + b0);
    }
    plane_mark(plP, local);

  } else if (isAtt && local < 1024) {
    // ========== attn: flash-decode partials ==========
    int mb = local - 768;
    int sp = mb & 7, n = (mb >> 3) & 15, b = mb >> 7;
    const float* kcL = kc + (size_t)att * BATCH * SEQ * NHEADS * HDIM;
    const float* vcL = vc + (size_t)att * BATCH * SEQ * NHEADS * HDIM;
    int pos = *posp;
    plane_wait<3>(plP);
    if (tid < 64) {
      int d = tid, j = d & 31;
      float cs = cosT[pos * 32 + j], sn = sinT[pos * 32 + j];
      float2 zq  = ald2(&z2[n * 64 + d]);
      float2 zqo = ald2(&z2[n * 64 + ((d + 32) & 63)]);
      float2 zk  = ald2(&z2[1024 + n * 64 + d]);
      float2 zko = ald2(&z2[1024 + n * 64 + ((d + 32) & 63)]);
      float2 zv  = ald2(&z2[2048 + n * 64 + d]);
      float qv = b ? zq.y : zq.x,  qo = b ? zqo.y : zqo.x;
      float kv = b ? zk.y : zk.x,  ko = b ? zko.y : zko.x;
      sh.att.q[d] = ((d < 32) ? (qv * cs - qo * sn) : (qv * cs + qo * sn)) * 0.125f;
      sh.att.k[d] = (d < 32) ? (kv * cs - ko * sn) : (kv * cs + ko * sn);
      sh.att.v[d] = b ? zv.y : zv.x;
    }
    __syncthreads();
    int s = sp * 256 + tid;
    float logit = -1e30f;
    if (s <= pos) {
      const float4* k4 = (s == pos) ? (const float4*)sh.att.k
                                    : (const float4*)(kcL + (((size_t)b * SEQ + s) * NHEADS + n) * HDIM);
      const float4* q4 = (const float4*)sh.att.q;
      float acc = 0.f;
#pragma unroll
      for (int j = 0; j < 16; j++) acc += dot4(k4[j], q4[j]);
      logit = acc;
    }
    float m = wredMax(logit);
    if (lane == 0) sh.att.redA[w] = m;
    __syncthreads();
    m = fmaxf(fmaxf(sh.att.redA[0], sh.att.redA[1]), fmaxf(sh.att.redA[2], sh.att.redA[3]));
    float e = (s <= pos) ? expf(logit - m) : 0.f;
    sh.att.eg[tid] = e;
    float ps = wredSum(e);
    __syncthreads();
    if (lane == 0) sh.att.redA[w] = ps;
    __syncthreads();
    float lsum = sh.att.redA[0] + sh.att.redA[1] + sh.att.redA[2] + sh.att.redA[3];
    int dgrp = lane & 15, srow = lane >> 4;
    float4 acc = make_float4(0.f, 0.f, 0.f, 0.f);
#pragma unroll 4
    for (int it = 0; it < 16; it++) {
      int sl = w * 64 + it * 4;
      if (sp * 256 + sl > pos) break;            // uniform within wave
      int sli = sl + srow;
      int ss2 = sp * 256 + sli;
      float ev = sh.att.eg[sli];
      const float4* v4 = (ss2 == pos) ? (const float4*)sh.att.v
                                      : (const float4*)(vcL + (((size_t)b * SEQ + ss2) * NHEADS + n) * HDIM);
      float4 vv = v4[dgrp];
      acc.x += ev * vv.x; acc.y += ev * vv.y; acc.z += ev * vv.z; acc.w += ev * vv.w;
    }
#pragma unroll
    for (int mm = 16; mm <= 32; mm <<= 1) {
      acc.x += __shfl_xor(acc.x, mm, 64);
      acc.y += __shfl_xor(acc.y, mm, 64);
      acc.z += __shfl_xor(acc.z, mm, 64);
      acc.w += __shfl_xor(acc.w, mm, 64);
    }
    if (srow == 0) ((float4*)sh.att.osum[w])[dgrp] = acc;
    __syncthreads();
    float* Pp = attP + (size_t)((sp * BATCH + b) * NHEADS + n) * 66;
    if (tid < 64) ast(&Pp[tid], sh.att.osum[0][tid] + sh.att.osum[1][tid] + sh.att.osum[2][tid] + sh.att.osum[3][tid]);
    if (tid == 64) ast(&Pp[64], m);
    if (tid == 65) ast(&Pp[65], lsum);
    plane_mark(plAtt, mb);

  } else if (local < w1Base) {
    // ========== mix: y (or attn-combine) -> oW GEMV + residual -> xM2 =====
    int mb = local - mixBase;
    int r = mb * 4 + w;
    const float4* rowp = (const float4*)(oWL + (size_t)r * H);
    float4 wv0 = rowp[lane], wv1 = rowp[lane + 64],
           wv2 = rowp[lane + 128], wv3 = rowp[lane + 192];
    if (!isAtt) {
      plane_wait<1>(plP);
#pragma unroll
      for (int k = 0; k < 4; k++) {
        int c = tid + k * 256;
        float2 t = ald2(&y2[c]);
        sh.mx.ys[c] = t.x;
        sh.mx.ys[1024 + c] = t.y;
      }
    } else {
      plane_wait<1>(plAtt);
      if (tid < 256) {
        int sp = tid & 7, n = (tid >> 3) & 15, b = tid >> 7;
        const float* Pp = attP + (size_t)((sp * BATCH + b) * NHEADS + n) * 66;
        sh.mx.sml[tid * 2] = ald(&Pp[64]);
        sh.mx.sml[tid * 2 + 1] = ald(&Pp[65]);
      }
      __syncthreads();
#pragma unroll
      for (int it = 0; it < 8; it++) {
        int e = tid + it * 256;
        int b = e >> 10, c = e & 1023;
        int n = c >> 6, d = c & 63;
        float M = -1e30f;
#pragma unroll
        for (int sp = 0; sp < 8; sp++) M = fmaxf(M, sh.mx.sml[(((b << 4) | n) * 8 + sp) * 2]);
        float Ls = 0.f, num = 0.f;
#pragma unroll
        for (int sp = 0; sp < 8; sp++) {
          float Msp = sh.mx.sml[(((b << 4) | n) * 8 + sp) * 2];
          float Lsp = sh.mx.sml[(((b << 4) | n) * 8 + sp) * 2 + 1];
          float wgt = expf(Msp - M);
          Ls += wgt * Lsp;
          num += wgt * ald(&attP[(size_t)((sp * BATCH + b) * NHEADS + n) * 66 + d]);
        }
        sh.mx.ys[e] = num / Ls;
      }
    }
    __syncthreads();
    const float4* y4 = (const float4*)sh.mx.ys;
    float a0 = dot4(wv0, y4[lane])       + dot4(wv1, y4[lane + 64])
             + dot4(wv2, y4[lane + 128]) + dot4(wv3, y4[lane + 192]);
    float a1 = dot4(wv0, y4[lane + 256]) + dot4(wv1, y4[lane + 320])
             + dot4(wv2, y4[lane + 384]) + dot4(wv3, y4[lane + 448]);
    a0 = wredSum(a0); a1 = wredSum(a1);
    if (lane == 0) {
      float obv = obL[r];
      ast2(&xM2[r], a0 + obv + xin[r], a1 + obv + xin[H + r]);
    }
    plane_mark(plMix, mb);

  } else if (local < w2Base) {
    // ========== W1: rmsnorm(xM2) + W1 GEMV + gelu -> h2 ==========
    int wb = local - w1Base;
    int r = wb * 4 + w;
    const float4* rowp = (const float4*)(W1L + (size_t)r * H);
    float4 wv0 = rowp[lane], wv1 = rowp[lane + 64],
           wv2 = rowp[lane + 128], wv3 = rowp[lane + 192];
    plane_wait<1>(plMix);
    float ss0 = 0.f, ss1 = 0.f;
#pragma unroll
    for (int k = 0; k < 4; k++) {
      int c = tid + k * 256;
      float2 xv = ald2(&xM2[c]);
      ss0 += xv.x * xv.x; ss1 += xv.y * xv.y;
      float nvj = n2L[c];
      sh.ns.xe[c] = xv.x * nvj;
      sh.ns.xe[1024 + c] = xv.y * nvj;
    }
    ss0 = wredSum(ss0); ss1 = wredSum(ss1);
    if (lane == 0) { sh.ns.red[w] = ss0; sh.ns.red[4 + w] = ss1; }
    __syncthreads();
    float s0 = rsqrtf((sh.ns.red[0] + sh.ns.red[1] + sh.ns.red[2] + sh.ns.red[3]) * (1.0f / H) + EPSF);
    float s1 = rsqrtf((sh.ns.red[4] + sh.ns.red[5] + sh.ns.red[6] + sh.ns.red[7]) * (1.0f / H) + EPSF);
    const float4* x4 = (const float4*)sh.ns.xe;
    float a0 = dot4(wv0, x4[lane])       + dot4(wv1, x4[lane + 64])
             + dot4(wv2, x4[lane + 128]) + dot4(wv3, x4[lane + 192]);
    float a1 = dot4(wv0, x4[lane + 256]) + dot4(wv1, x4[lane + 320])
             + dot4(wv2, x4[lane + 384]) + dot4(wv3, x4[lane + 448]);
    a0 = wredSum(a0); a1 = wredSum(a1);
    if (lane == 0) ast2(&h2[r], gelu_t(a0 * s0), gelu_t(a1 * s1));
    plane_mark(plW1, wb);

  } else {
    // ========== W2: W2 GEMV + residual -> xout ==========
    int vb = local - w2Base;
    int r = vb * 4 + w;
    const float4* rowp = (const float4*)(W2L + (size_t)r * FF);
    float4 wv[8];
#pragma unroll
    for (int j = 0; j < 8; j++) wv[j] = rowp[lane + 64 * j];
    plane_wait<2>(plW1);
#pragma unroll
    for (int it = 0; it < 8; it++) {
      int e = tid + it * 256;
      float2 hv = ald2(&h2[e]);
      sh.w2.hs[e] = hv.x;
      sh.w2.hs[2048 + e] = hv.y;
    }
    __syncthreads();
    const float4* h4 = (const float4*)sh.w2.hs;
    float a0 = 0.f, a1 = 0.f;
#pragma unroll
    for (int j = 0; j < 8; j++) {
      a0 += dot4(wv[j], h4[lane + 64 * j]);
      a1 += dot4(wv[j], h4[lane + 64 * j + 512]);
    }
    a0 = wredSum(a0); a1 = wredSum(a1);
    if (lane == 0) {
      float2 xm = ald2(&xM2[r]);
      xout[r]     = a0 + xm.x;
      xout[H + r] = a1 + xm.y;
    }
  }
}

// ---------------------------------------------------------------------------
// prep: hoist state-linear terms (r1-verified) + zero sync planes (1MB)
// ---------------------------------------------------------------------------
__global__ __launch_bounds__(256) void prep_kernel(
    const float* __restrict__ sf_w, const float* __restrict__ sf_b,
    const float* __restrict__ fir_state,
    const float* __restrict__ hcs_h, const float* __restrict__ hcs_D, const float* __restrict__ hcs_state,
    const float* __restrict__ hcm_h, const float* __restrict__ hcm_D, const float* __restrict__ hcm_state,
    const float* __restrict__ lp, const float* __restrict__ resd, const float* __restrict__ hcl_D,
    const float* __restrict__ iir,
    unsigned long long kbits,
    float* __restrict__ sfd, float* __restrict__ sfc,
    float* __restrict__ mix0, float* __restrict__ mix1, int* __restrict__ bar)
{
  int blk = blockIdx.x, tid = threadIdx.x;
  if (blk < 768) {
    int idx = blk * 256 + tid;
    int i = idx / (BATCH * H3);
    int r = idx % (BATCH * H3);
    int b = r / H3, ch = r % H3;
    const float* fs = fir_state + ((size_t)(i * BATCH + b) * H3 + ch) * 2;
    const float* sw = sf_w + ((size_t)i * H3 + ch) * 3;
    sfd[(size_t)i * 2 * H3 + b * H3 + ch] = fs[0] * sw[0] + fs[1] * sw[1] + sf_b[i * H3 + ch];
    if (b == 0) sfc[i * H3 + ch] = sw[2];
  } else if (blk < 1024) {
    int idx = (blk - 768) * 256 + tid;
    int i = idx >> 11;
    int r = idx & 2047;
    int b = r >> 10, c = r & 1023;
    int kind = (int)((kbits >> (2 * i)) & 3ull);
    if (kind == 0) {
      const float* st = hcs_state + ((size_t)(i * BATCH + b) * H + c) * 6;
      const float* hh = hcs_h + ((size_t)i * H + c) * 7;
      float acc = 0.f;
#pragma unroll
      for (int k = 0; k < 6; k++) acc += st[k] * hh[k];
      mix0[idx] = acc + hcs_D[i * H + c];
      if (b == 0) mix1[i * H + c] = hh[6];
    } else if (kind == 2) {
      const float* ii = iir + ((size_t)(i * BATCH + b) * H + c) * 16;
      const float* lpp = lp + ((size_t)i * H + c) * 16;
      const float* rs = resd + ((size_t)i * H + c) * 16;
      float acc = 0.f, rsum = 0.f;
#pragma unroll
      for (int k = 0; k < 16; k++) { float rv = rs[k]; acc += rv * expf(lpp[k]) * ii[k]; rsum += rv; }
      mix0[idx] = acc;
      if (b == 0) mix1[i * H + c] = rsum + hcl_D[i * H + c];
    }
  } else if (blk < 5632) {
    int w = tid >> 6, lane = tid & 63;
    int widx = (blk - 1024) * 4 + w;
    if (widx < 9 * BATCH * H) {
      int li = widx >> 11;
      int r = widx & 2047;
      int b = r >> 10, c = r & 1023;
      int i = (li >> 1) * 7 + ((li & 1) ? 5 : 1);  // HCM layers 1,5,8,12,15,19,22,26,29
      const float* st = hcm_state + ((size_t)(i * BATCH + b) * H + c) * 127;
      const float* hh = hcm_h + ((size_t)i * H + c) * 128;
      float acc = 0.f;
      int k = lane;
      if (k < 127) acc += st[k] * hh[127 - k];
      k = lane + 64;
      if (k < 127) acc += st[k] * hh[127 - k];
      acc = wredSum(acc);
      if (lane == 0) {
        mix0[(i * BATCH + b) * H + c] = acc;
        if (b == 0) mix1[i * H + c] = hh[0] + hcm_D[i * H + c];
      }
    }
  } else {
    int idx = (blk - 5632) * 256 + tid;
    if (idx < LAYERS * 8192) bar[idx] = 0;   // 32 x 32KB planes
  }
}

// ---------------------------------------------------------------------------
extern "C" void kernel_launch(void* const* d_in, const int* in_sizes, int n_in,
                              void* d_out, int out_size, void* d_ws, size_t ws_size,
                              hipStream_t stream) {
  (void)in_sizes; (void)n_in; (void)out_size; (void)ws_size;
  const float* x0    = (const float*)d_in[0];
  const int*   posp  = (const int*)d_in[1];
  const float* n1    = (const float*)d_in[2];
  const float* n2    = (const float*)d_in[3];
  const float* pW    = (const float*)d_in[4];
  const float* pb    = (const float*)d_in[5];
  const float* oW    = (const float*)d_in[6];
  const float* ob    = (const float*)d_in[7];
  const float* W1    = (const float*)d_in[8];
  const float* W2    = (const float*)d_in[9];
  const float* sfw   = (const float*)d_in[10];
  const float* sfb   = (const float*)d_in[11];
  const float* hcs_h = (const float*)d_in[12];
  const float* hcs_D = (const float*)d_in[13];
  const float* hcm_h = (const float*)d_in[14];
  const float* hcm_D = (const float*)d_in[15];
  const float* lp    = (const float*)d_in[16];
  const float* resd  = (const float*)d_in[17];
  const float* hclD  = (const float*)d_in[18];
  const float* fir   = (const float*)d_in[19];
  const float* hcsS  = (const float*)d_in[20];
  const float* hcmS  = (const float*)d_in[21];
  const float* iir   = (const float*)d_in[22];
  const float* kc    = (const float*)d_in[23];
  const float* vc    = (const float*)d_in[24];
  const float* cosT  = (const float*)d_in[25];
  const float* sinT  = (const float*)d_in[26];

  float* ws    = (float*)d_ws;
  float* xbuf0 = ws;                                            // 2048
  float* xbuf1 = ws + 2048;                                     // 2048
  unsigned long long* y2  = (unsigned long long*)(ws + 4096);   // 1024 ull
  unsigned long long* z2  = (unsigned long long*)(ws + 6144);   // 3072 ull
  unsigned long long* xM2 = (unsigned long long*)(ws + 12288);  // 1024 ull
  unsigned long long* h2  = (unsigned long long*)(ws + 14336);  // 2048 ull
  float* attP  = ws + 18432;          // 16896
  float* sfd   = ws + 35328;          // 196608
  float* sfc   = ws + 231936;         // 98304
  float* mix0  = ws + 330240;         // 65536
  float* mix1  = ws + 395776;         // 32768
  int*   bar   = (int*)(ws + 428544); // 32 layers x 8192 ints (32KB planes)

  static const int KIND[LAYERS] = {0,1,2,3,0,1,2,0,1,2,3,0,1,2,0,1,2,3,0,1,2,0,1,2,3,0,1,2,0,1,2,3};
  unsigned long long kbits = 0ull;
  for (int i = 0; i < LAYERS; i++) kbits |= ((unsigned long long)KIND[i]) << (2 * i);

  int zblocks = (LAYERS * 8192 + 255) / 256;  // 1024
  prep_kernel<<<5632 + zblocks, 256, 0, stream>>>(sfw, sfb, fir, hcs_h, hcs_D, hcsS,
      hcm_h, hcm_D, hcmS, lp, resd, hclD, iir, kbits, sfd, sfc, mix0, mix1, bar);

  const float* xsrc = x0;
  int att = 0;
  for (int i = 0; i < LAYERS; i++) {
    int kind = KIND[i];
    int nb = (kind == 3) ? 2048 : 1280;
    float* xout = (i == LAYERS - 1) ? (float*)d_out : ((i & 1) ? xbuf1 : xbuf0);
    layer_k<<<nb, 256, 0, stream>>>(
        kind, att, xsrc, xout,
        n1 + (size_t)i * H, n2 + (size_t)i * H,
        pW + (size_t)i * H3 * H, pb + (size_t)i * H3,
        oW + (size_t)i * H * H, ob + (size_t)i * H,
        W1 + (size_t)i * FF * H, W2 + (size_t)i * H * FF,
        sfc + (size_t)i * H3, sfd + (size_t)i * 2 * H3,
        mix0 + (size_t)i * 2 * H, mix1 + (size_t)i * H,
        kc, vc, posp, cosT, sinT,
        z2, y2, attP, xM2, h2,
        (unsigned char*)(bar + (size_t)i * 8192));
    if (kind == 3) att++;
    xsrc = xout;
  }
}

// Round 12
// 757.862 us; speedup vs baseline: 1.4876x; 1.1700x over previous
//
#include <hip/hip_runtime.h>
#include <hip/hip_bf16.h>
#include <math.h>

#define LAYERS 32
#define H      1024
#define H3     3072
#define NHEADS 16
#define HDIM   64
#define FF     2048
#define BATCH  2
#define SEQ    2048
#define EPSF   1e-6f

__device__ __forceinline__ float wredSum(float v) {
#pragma unroll
  for (int m = 32; m >= 1; m >>= 1) v += __shfl_xor(v, m, 64);
  return v;
}
__device__ __forceinline__ float wredMax(float v) {
#pragma unroll
  for (int m = 32; m >= 1; m >>= 1) v = fmaxf(v, __shfl_xor(v, m, 64));
  return v;
}
__device__ __forceinline__ float gelu_t(float x) {
  return 0.5f * x * (1.0f + tanhf(0.7978845608028654f * (x + 0.044715f * x * x * x)));
}
__device__ __forceinline__ float dot4(float4 a, float4 b) {
  return a.x * b.x + a.y * b.y + a.z * b.z + a.w * b.w;
}

// bounded prefetch: one 32KB chunk (2048 float4) per block, 8 rounds x 256 thr.
// Pulls next-layer weights through HBM into the memory-side Infinity Cache
// during the current slot's dead time. Values kept live via asm.
__device__ __forceinline__ void pf32(const float4* __restrict__ p, int chunk) {
  const float4* b = p + (size_t)chunk * 2048 + threadIdx.x;
  float a0 = 0.f, a1 = 0.f, a2 = 0.f, a3 = 0.f;
#pragma unroll
  for (int k = 0; k < 8; k++) {
    float4 v = b[k * 256];
    a0 += v.x; a1 += v.y; a2 += v.z; a3 += v.w;
  }
  asm volatile("" :: "v"(a0), "v"(a1), "v"(a2), "v"(a3));
}

// ---------------------------------------------------------------------------
// prep: hoist all state-linear terms (r1-verified) + prefetch layer 0 weights
// ---------------------------------------------------------------------------
__global__ __launch_bounds__(256) void prep_kernel(
    const float* __restrict__ sf_w, const float* __restrict__ sf_b,
    const float* __restrict__ fir_state,
    const float* __restrict__ hcs_h, const float* __restrict__ hcs_D, const float* __restrict__ hcs_state,
    const float* __restrict__ hcm_h, const float* __restrict__ hcm_D, const float* __restrict__ hcm_state,
    const float* __restrict__ lp, const float* __restrict__ resd, const float* __restrict__ hcl_D,
    const float* __restrict__ iir,
    unsigned long long kbits,
    float* __restrict__ sfd, float* __restrict__ sfc,
    float* __restrict__ mix0, float* __restrict__ mix1,
    const float4* __restrict__ pW0, const float4* __restrict__ oW0,
    const float4* __restrict__ W10, const float4* __restrict__ W20)
{
  int blk = blockIdx.x, tid = threadIdx.x;
  if (blk >= 5632) {
    int idx = blk - 5632;                   // 1024 chunks = 32 MB (layer 0)
    if (idx < 384) pf32(pW0, idx);
    else if (idx < 512) pf32(oW0, idx - 384);
    else if (idx < 768) pf32(W10, idx - 512);
    else pf32(W20, idx - 768);
    return;
  }
  if (blk < 768) {
    int idx = blk * 256 + tid;
    int i = idx / (BATCH * H3);
    int r = idx % (BATCH * H3);
    int b = r / H3, ch = r % H3;
    const float* fs = fir_state + ((size_t)(i * BATCH + b) * H3 + ch) * 2;
    const float* sw = sf_w + ((size_t)i * H3 + ch) * 3;
    sfd[idx] = fs[0] * sw[0] + fs[1] * sw[1] + sf_b[i * H3 + ch];
    if (b == 0) sfc[i * H3 + ch] = sw[2];
  } else if (blk < 1024) {
    int idx = (blk - 768) * 256 + tid;
    int i = idx >> 11;
    int r = idx & 2047;
    int b = r >> 10, c = r & 1023;
    int kind = (int)((kbits >> (2 * i)) & 3ull);
    if (kind == 0) {
      const float* st = hcs_state + ((size_t)(i * BATCH + b) * H + c) * 6;
      const float* hh = hcs_h + ((size_t)i * H + c) * 7;
      float acc = 0.f;
#pragma unroll
      for (int k = 0; k < 6; k++) acc += st[k] * hh[k];
      mix0[idx] = acc + hcs_D[i * H + c];
      if (b == 0) mix1[i * H + c] = hh[6];
    } else if (kind == 2) {
      const float* ii = iir + ((size_t)(i * BATCH + b) * H + c) * 16;
      const float* lpp = lp + ((size_t)i * H + c) * 16;
      const float* rs = resd + ((size_t)i * H + c) * 16;
      float acc = 0.f, rsum = 0.f;
#pragma unroll
      for (int k = 0; k < 16; k++) { float rv = rs[k]; acc += rv * expf(lpp[k]) * ii[k]; rsum += rv; }
      mix0[idx] = acc;
      if (b == 0) mix1[i * H + c] = rsum + hcl_D[i * H + c];
    }
  } else {
    int w = tid >> 6, lane = tid & 63;
    int widx = (blk - 1024) * 4 + w;
    if (widx < 9 * BATCH * H) {
      int li = widx >> 11;
      int r = widx & 2047;
      int b = r >> 10, c = r & 1023;
      int i = (li >> 1) * 7 + ((li & 1) ? 5 : 1);  // HCM layers 1,5,8,12,15,19,22,26,29
      const float* st = hcm_state + ((size_t)(i * BATCH + b) * H + c) * 127;
      const float* hh = hcm_h + ((size_t)i * H + c) * 128;
      float acc = 0.f;
      int k = lane;
      if (k < 127) acc += st[k] * hh[127 - k];
      k = lane + 64;
      if (k < 127) acc += st[k] * hh[127 - k];
      acc = wredSum(acc);
      if (lane == 0) {
        mix0[(i * BATCH + b) * H + c] = acc;
        if (b == 0) mix1[i * H + c] = hh[0] + hcm_D[i * H + c];
      }
    }
  }
}

// ---------------------------------------------------------------------------
// P / W1: fused rmsnorm + GEMV (r6-verified) + bounded next-layer prefetch
// ---------------------------------------------------------------------------
template<int ROWS, bool GELU, bool HASBIAS>
__global__ __launch_bounds__(256) void gemv_norm(
    const float* __restrict__ x, const float* __restrict__ nw,
    const float* __restrict__ W, const float* __restrict__ bias,
    float* __restrict__ out,
    const float4* __restrict__ f0, int c0,
    const float4* __restrict__ f1, int c1,
    const float4* __restrict__ f2, int c2)
{
  __shared__ alignas(16) float xe[BATCH * H];
  __shared__ float red[8];
  int tid = threadIdx.x, lane = tid & 63, w = tid >> 6;
  const int NFUNC = ROWS / 4;
  if (blockIdx.x >= NFUNC) {
    int idx = blockIdx.x - NFUNC;
    if (idx < c0) pf32(f0, idx);
    else if (idx < c0 + c1) pf32(f1, idx - c0);
    else if (idx < c0 + c1 + c2) pf32(f2, idx - c0 - c1);
    return;
  }

  // x loads first (norm depends only on these), weights stream underneath
  float4 xv0 = ((const float4*)x)[tid];
  float4 xv1 = ((const float4*)x)[tid + 256];
  float4 nv  = ((const float4*)nw)[tid];
  int r = blockIdx.x * 4 + w;
  const float4* rowp = (const float4*)(W + (size_t)r * H);
  float4 wv0 = rowp[lane], wv1 = rowp[lane + 64],
         wv2 = rowp[lane + 128], wv3 = rowp[lane + 192];

  float ss0 = dot4(xv0, xv0), ss1 = dot4(xv1, xv1);
  ((float4*)xe)[tid]       = make_float4(xv0.x * nv.x, xv0.y * nv.y, xv0.z * nv.z, xv0.w * nv.w);
  ((float4*)xe)[tid + 256] = make_float4(xv1.x * nv.x, xv1.y * nv.y, xv1.z * nv.z, xv1.w * nv.w);
  ss0 = wredSum(ss0); ss1 = wredSum(ss1);
  if (lane == 0) { red[w] = ss0; red[4 + w] = ss1; }
  __syncthreads();
  float s0 = rsqrtf((red[0] + red[1] + red[2] + red[3]) * (1.0f / H) + EPSF);
  float s1 = rsqrtf((red[4] + red[5] + red[6] + red[7]) * (1.0f / H) + EPSF);

  const float4* x4 = (const float4*)xe;
  float a0 = dot4(wv0, x4[lane])       + dot4(wv1, x4[lane + 64])
           + dot4(wv2, x4[lane + 128]) + dot4(wv3, x4[lane + 192]);
  float a1 = dot4(wv0, x4[lane + 256]) + dot4(wv1, x4[lane + 320])
           + dot4(wv2, x4[lane + 384]) + dot4(wv3, x4[lane + 448]);
  a0 = wredSum(a0); a1 = wredSum(a1);
  if (lane == 0) {
    float b0 = HASBIAS ? bias[r] : 0.f;
    float v0 = a0 * s0 + b0, v1 = a1 * s1 + b0;
    if (GELU) { v0 = gelu_t(v0); v1 = gelu_t(v1); }
    out[r] = v0;
    out[ROWS + r] = v1;
  }
}

// ---------------------------------------------------------------------------
// mixer (redundant per block) + out_W GEMV + bias + residual -> xM  (+pf)
// ---------------------------------------------------------------------------
__global__ __launch_bounds__(256) void mix_out_kernel(
    int kind,
    const float* __restrict__ z, const float* __restrict__ sfdL, const float* __restrict__ sfcL,
    const float* __restrict__ mix0L, const float* __restrict__ mix1L,
    const float* __restrict__ attP,
    const float* __restrict__ oW, const float* __restrict__ ob,
    const float* __restrict__ x_in, float* __restrict__ x_out,
    const float4* __restrict__ f0, int c0)
{
  __shared__ alignas(16) float ys[BATCH * H];
  int tid = threadIdx.x, lane = tid & 63, w = tid >> 6;
  if (blockIdx.x >= 256) {
    int idx = blockIdx.x - 256;
    if (idx < c0) pf32(f0, idx);
    return;
  }
  int r = blockIdx.x * 4 + w;

  if (kind < 3) {
    float x2v[8], x1v[8], vvv[8];
#pragma unroll
    for (int it = 0; it < 8; it++) {
      int e = tid + it * 256;
      int b = e >> 10, c = e & 1023;
      int n = c >> 6, d = c & 63;
      int base = n * 192 + d;
      x2v[it] = sfcL[base] * z[b * H3 + base] + sfdL[b * H3 + base];
      x1v[it] = sfcL[base + 64] * z[b * H3 + base + 64] + sfdL[b * H3 + base + 64];
      vvv[it] = sfcL[base + 128] * z[b * H3 + base + 128] + sfdL[b * H3 + base + 128];
    }
    const float4* rowp = (const float4*)(oW + (size_t)r * H);
    float4 wv0 = rowp[lane], wv1 = rowp[lane + 64],
           wv2 = rowp[lane + 128], wv3 = rowp[lane + 192];
#pragma unroll
    for (int it = 0; it < 8; it++) {
      int e = tid + it * 256;
      int b = e >> 10, c = e & 1023;
      float t = x1v[it] * vvv[it];
      ys[e] = (mix1L[c] * t + mix0L[b * H + c]) * x2v[it];
    }
    __syncthreads();
    const float4* y4 = (const float4*)ys;
    float a0 = dot4(wv0, y4[lane])       + dot4(wv1, y4[lane + 64])
             + dot4(wv2, y4[lane + 128]) + dot4(wv3, y4[lane + 192]);
    float a1 = dot4(wv0, y4[lane + 256]) + dot4(wv1, y4[lane + 320])
             + dot4(wv2, y4[lane + 384]) + dot4(wv3, y4[lane + 448]);
    a0 = wredSum(a0); a1 = wredSum(a1);
    if (lane == 0) {
      x_out[r]     = a0 + ob[r] + x_in[r];
      x_out[H + r] = a1 + ob[r] + x_in[H + r];
    }
  } else {
    const float4* rowp = (const float4*)(oW + (size_t)r * H);
    float4 wv0 = rowp[lane], wv1 = rowp[lane + 64],
           wv2 = rowp[lane + 128], wv3 = rowp[lane + 192];
#pragma unroll
    for (int it = 0; it < 8; it++) {
      int e = tid + it * 256;
      int b = e >> 10, c = e & 1023;
      int n = c >> 6, d = c & 63;
      float M = -1e30f;
#pragma unroll
      for (int sp = 0; sp < 8; sp++) M = fmaxf(M, attP[((sp * BATCH + b) * NHEADS + n) * 66 + 64]);
      float Ls = 0.f, num = 0.f;
#pragma unroll
      for (int sp = 0; sp < 8; sp++) {
        const float* P = attP + ((sp * BATCH + b) * NHEADS + n) * 66;
        float wgt = expf(P[64] - M);
        Ls += wgt * P[65];
        num += wgt * P[d];
      }
      ys[e] = num / Ls;
    }
    __syncthreads();
    const float4* y4 = (const float4*)ys;
    float a0 = dot4(wv0, y4[lane])       + dot4(wv1, y4[lane + 64])
             + dot4(wv2, y4[lane + 128]) + dot4(wv3, y4[lane + 192]);
    float a1 = dot4(wv0, y4[lane + 256]) + dot4(wv1, y4[lane + 320])
             + dot4(wv2, y4[lane + 384]) + dot4(wv3, y4[lane + 448]);
    a0 = wredSum(a0); a1 = wredSum(a1);
    if (lane == 0) {
      x_out[r]     = a0 + ob[r] + x_in[r];
      x_out[H + r] = a1 + ob[r] + x_in[H + r];
    }
  }
}

// ---------------------------------------------------------------------------
// W2 GEMV + residual (r6-verified) + bounded next-layer prefetch
// ---------------------------------------------------------------------------
__global__ __launch_bounds__(256) void gemv_mlp2(
    const float* __restrict__ h, const float* __restrict__ W2,
    const float* __restrict__ xM, float* __restrict__ x_out,
    const float4* __restrict__ f0, int c0,
    const float4* __restrict__ f1, int c1)
{
  __shared__ alignas(16) float hs[BATCH * FF];
  int tid = threadIdx.x, lane = tid & 63, w = tid >> 6;
  if (blockIdx.x >= 256) {
    int idx = blockIdx.x - 256;
    if (idx < c0) pf32(f0, idx);
    else if (idx < c0 + c1) pf32(f1, idx - c0);
    return;
  }
  float4 h0 = ((const float4*)h)[tid];
  float4 h1 = ((const float4*)h)[tid + 256];
  float4 h2 = ((const float4*)h)[tid + 512];
  float4 h3 = ((const float4*)h)[tid + 768];
  int r = blockIdx.x * 4 + w;
  const float4* rowp = (const float4*)(W2 + (size_t)r * FF);
  float4 wv[8];
#pragma unroll
  for (int j = 0; j < 8; j++) wv[j] = rowp[lane + 64 * j];

  ((float4*)hs)[tid]       = h0;
  ((float4*)hs)[tid + 256] = h1;
  ((float4*)hs)[tid + 512] = h2;
  ((float4*)hs)[tid + 768] = h3;
  __syncthreads();

  const float4* h4 = (const float4*)hs;
  float a0 = 0.f, a1 = 0.f;
#pragma unroll
  for (int j = 0; j < 8; j++) {
    a0 += dot4(wv[j], h4[lane + 64 * j]);
    a1 += dot4(wv[j], h4[lane + 64 * j + 512]);
  }
  a0 = wredSum(a0); a1 = wredSum(a1);
  if (lane == 0) {
    x_out[r]     = a0 + xM[r];
    x_out[H + r] = a1 + xM[H + r];
  }
}

// ---------------------------------------------------------------------------
// flash-decode attention partials (r1-verified): 8 splits x 16 heads x 2 batch
// ---------------------------------------------------------------------------
__global__ __launch_bounds__(256) void attn_kernel(
    const float* __restrict__ z, const int* __restrict__ posp,
    const float* __restrict__ kc, const float* __restrict__ vc,
    const float* __restrict__ cosT, const float* __restrict__ sinT,
    float* __restrict__ P)
{
  int sp = blockIdx.x & 7, n = (blockIdx.x >> 3) & 15, b = blockIdx.x >> 7;
  int pos = *posp;
  __shared__ alignas(16) float q_s[HDIM], k_s[HDIM], v_s[HDIM];
  __shared__ float eg[256];
  __shared__ float redA[4];
  __shared__ alignas(16) float osum[4][HDIM];
  int tid = threadIdx.x, lane = tid & 63, w = tid >> 6;

  if (tid < 64) {
    int d = tid, j = d & 31;
    float cs = cosT[pos * 32 + j], sn = sinT[pos * 32 + j];
    float qv = z[b * H3 + n * 64 + d];
    float qo = z[b * H3 + n * 64 + ((d + 32) & 63)];
    q_s[d] = ((d < 32) ? (qv * cs - qo * sn) : (qv * cs + qo * sn)) * 0.125f;
    float kv = z[b * H3 + 1024 + n * 64 + d];
    float ko = z[b * H3 + 1024 + n * 64 + ((d + 32) & 63)];
    k_s[d] = (d < 32) ? (kv * cs - ko * sn) : (kv * cs + ko * sn);
    v_s[d] = z[b * H3 + 2048 + n * 64 + d];
  }
  __syncthreads();

  int s = sp * 256 + tid;
  float logit = -1e30f;
  if (s <= pos) {
    const float4* k4 = (s == pos) ? (const float4*)k_s
                                  : (const float4*)(kc + (((size_t)b * SEQ + s) * NHEADS + n) * HDIM);
    const float4* q4 = (const float4*)q_s;
    float acc = 0.f;
#pragma unroll
    for (int j = 0; j < 16; j++) acc += dot4(k4[j], q4[j]);
    logit = acc;
  }
  float m = wredMax(logit);
  if (lane == 0) redA[w] = m;
  __syncthreads();
  m = fmaxf(fmaxf(redA[0], redA[1]), fmaxf(redA[2], redA[3]));
  float e = (s <= pos) ? expf(logit - m) : 0.f;
  eg[tid] = e;
  float ps = wredSum(e);
  __syncthreads();
  if (lane == 0) redA[w] = ps;
  __syncthreads();
  float lsum = redA[0] + redA[1] + redA[2] + redA[3];

  int dgrp = lane & 15, srow = lane >> 4;
  float4 acc = make_float4(0.f, 0.f, 0.f, 0.f);
#pragma unroll 4
  for (int it = 0; it < 16; it++) {
    int sl = w * 64 + it * 4;
    if (sp * 256 + sl > pos) break;              // uniform within wave
    int sli = sl + srow;
    int ss = sp * 256 + sli;
    float ev = eg[sli];
    const float4* v4 = (ss == pos) ? (const float4*)v_s
                                   : (const float4*)(vc + (((size_t)b * SEQ + ss) * NHEADS + n) * HDIM);
    float4 vv = v4[dgrp];
    acc.x += ev * vv.x; acc.y += ev * vv.y; acc.z += ev * vv.z; acc.w += ev * vv.w;
  }
#pragma unroll
  for (int mm = 16; mm <= 32; mm <<= 1) {
    acc.x += __shfl_xor(acc.x, mm, 64);
    acc.y += __shfl_xor(acc.y, mm, 64);
    acc.z += __shfl_xor(acc.z, mm, 64);
    acc.w += __shfl_xor(acc.w, mm, 64);
  }
  if (srow == 0) ((float4*)osum[w])[dgrp] = acc;
  __syncthreads();
  float* Pp = P + ((size_t)(sp * BATCH + b) * NHEADS + n) * 66;
  if (tid < 64) Pp[tid] = osum[0][tid] + osum[1][tid] + osum[2][tid] + osum[3][tid];
  if (tid == 64) Pp[64] = m;
  if (tid == 65) Pp[65] = lsum;
}

// ---------------------------------------------------------------------------
extern "C" void kernel_launch(void* const* d_in, const int* in_sizes, int n_in,
                              void* d_out, int out_size, void* d_ws, size_t ws_size,
                              hipStream_t stream) {
  (void)in_sizes; (void)n_in; (void)out_size; (void)ws_size;
  const float* x0    = (const float*)d_in[0];
  const int*   posp  = (const int*)d_in[1];
  const float* n1    = (const float*)d_in[2];
  const float* n2    = (const float*)d_in[3];
  const float* pW    = (const float*)d_in[4];
  const float* pb    = (const float*)d_in[5];
  const float* oW    = (const float*)d_in[6];
  const float* ob    = (const float*)d_in[7];
  const float* W1    = (const float*)d_in[8];
  const float* W2    = (const float*)d_in[9];
  const float* sfw   = (const float*)d_in[10];
  const float* sfb   = (const float*)d_in[11];
  const float* hcs_h = (const float*)d_in[12];
  const float* hcs_D = (const float*)d_in[13];
  const float* hcm_h = (const float*)d_in[14];
  const float* hcm_D = (const float*)d_in[15];
  const float* lp    = (const float*)d_in[16];
  const float* resd  = (const float*)d_in[17];
  const float* hclD  = (const float*)d_in[18];
  const float* fir   = (const float*)d_in[19];
  const float* hcsS  = (const float*)d_in[20];
  const float* hcmS  = (const float*)d_in[21];
  const float* iir   = (const float*)d_in[22];
  const float* kc    = (const float*)d_in[23];
  const float* vc    = (const float*)d_in[24];
  const float* cosT  = (const float*)d_in[25];
  const float* sinT  = (const float*)d_in[26];

  float* ws    = (float*)d_ws;
  float* xbuf0 = ws;                 // 2048
  float* xbuf1 = ws + 2048;          // 2048
  float* xM    = ws + 4096;          // 2048
  float* zbuf  = ws + 6144;          // 6144
  float* hbuf  = ws + 12288;         // 4096
  float* attP  = ws + 16384;         // 16896
  float* sfd   = ws + 33280;         // 196608
  float* sfc   = ws + 229888;        // 98304
  float* mix0  = ws + 328192;        // 65536
  float* mix1  = ws + 393728;        // 32768

  static const int KIND[LAYERS] = {0,1,2,3,0,1,2,0,1,2,3,0,1,2,0,1,2,3,0,1,2,0,1,2,3,0,1,2,0,1,2,3};
  unsigned long long kbits = 0ull;
  for (int i = 0; i < LAYERS; i++) kbits |= ((unsigned long long)KIND[i]) << (2 * i);

  prep_kernel<<<5632 + 1024, 256, 0, stream>>>(sfw, sfb, fir, hcs_h, hcs_D, hcsS,
      hcm_h, hcm_D, hcmS, lp, resd, hclD, iir, kbits, sfd, sfc, mix0, mix1,
      (const float4*)pW, (const float4*)oW, (const float4*)W1, (const float4*)W2);

  const float* xsrc = x0;
  int att = 0;
  for (int i = 0; i < LAYERS; i++) {
    int nx = i + 1;
    bool hasNext = (nx < LAYERS);
    const float4* pWn  = hasNext ? (const float4*)(pW + (size_t)nx * H3 * H) : (const float4*)pW;
    const float4* oWn  = hasNext ? (const float4*)(oW + (size_t)nx * H * H) : (const float4*)oW;
    const float4* W1n  = hasNext ? (const float4*)(W1 + (size_t)nx * FF * H) : (const float4*)W1;
    const float4* W2n  = hasNext ? (const float4*)(W2 + (size_t)nx * H * FF) : (const float4*)W2;
    int cm = hasNext ? 352 : 0;      // mix: pW(next)[0..352)
    int cw1a = hasNext ? 32 : 0;     // W1: pW(next)[352..384)
    int cw1b = hasNext ? 128 : 0;    //     oW(next)[0..128)
    int cw1c = hasNext ? 192 : 0;    //     W1(next)[0..192)
    int cw2a = hasNext ? 64 : 0;     // W2: W1(next)[192..256)
    int cw2b = hasNext ? 256 : 0;    //     W2(next)[0..256)

    gemv_norm<H3, false, true><<<H3 / 4, 256, 0, stream>>>(
        xsrc, n1 + i * H, pW + (size_t)i * H3 * H, pb + i * H3, zbuf,
        (const float4*)pW, 0, (const float4*)pW, 0, (const float4*)pW, 0);
    if (KIND[i] == 3) {
      attn_kernel<<<256, 256, 0, stream>>>(
          zbuf, posp, kc + (size_t)att * BATCH * SEQ * NHEADS * HDIM,
          vc + (size_t)att * BATCH * SEQ * NHEADS * HDIM, cosT, sinT, attP);
      att++;
    }
    mix_out_kernel<<<256 + cm, 256, 0, stream>>>(
        KIND[i], zbuf, sfd + (size_t)i * BATCH * H3, sfc + (size_t)i * H3,
        mix0 + (size_t)i * BATCH * H, mix1 + (size_t)i * H, attP,
        oW + (size_t)i * H * H, ob + i * H, xsrc, xM,
        pWn, cm);
    gemv_norm<FF, true, false><<<FF / 4 + cw1a + cw1b + cw1c, 256, 0, stream>>>(
        xM, n2 + i * H, W1 + (size_t)i * FF * H, nullptr, hbuf,
        pWn + (size_t)352 * 2048, cw1a, oWn, cw1b, W1n, cw1c);
    float* xout = (i == LAYERS - 1) ? (float*)d_out : ((i & 1) ? xbuf1 : xbuf0);
    gemv_mlp2<<<256 + cw2a + cw2b, 256, 0, stream>>>(
        hbuf, W2 + (size_t)i * H * FF, xM, xout,
        W1n + (size_t)192 * 2048, cw2a, W2n, cw2b);
    xsrc = xout;
  }
}

// Round 13
// 681.168 us; speedup vs baseline: 1.6551x; 1.1126x over previous
//
#include <hip/hip_runtime.h>
#include <hip/hip_bf16.h>
#include <math.h>

#define LAYERS 32
#define H      1024
#define H3     3072
#define NHEADS 16
#define HDIM   64
#define FF     2048
#define BATCH  2
#define SEQ    2048
#define EPSF   1e-6f

__device__ __forceinline__ float wredSum(float v) {
#pragma unroll
  for (int m = 32; m >= 1; m >>= 1) v += __shfl_xor(v, m, 64);
  return v;
}
__device__ __forceinline__ float wredMax(float v) {
#pragma unroll
  for (int m = 32; m >= 1; m >>= 1) v = fmaxf(v, __shfl_xor(v, m, 64));
  return v;
}
__device__ __forceinline__ float gelu_t(float x) {
  return 0.5f * x * (1.0f + tanhf(0.7978845608028654f * (x + 0.044715f * x * x * x)));
}
__device__ __forceinline__ float dot4(float4 a, float4 b) {
  return a.x * b.x + a.y * b.y + a.z * b.z + a.w * b.w;
}

// ---------------------------------------------------------------------------
// prep: hoist all state-linear terms (r1-verified).
//  sfd[i][b][ch] = fir_state.w0 + fir_state.w1 + sf_b   (zp = sfc*u + sfd)
//  mixer uniformized: y = (mix1[c]*x1*v + mix0[b][c]) * x2
// ---------------------------------------------------------------------------
__global__ __launch_bounds__(256) void prep_kernel(
    const float* __restrict__ sf_w, const float* __restrict__ sf_b,
    const float* __restrict__ fir_state,
    const float* __restrict__ hcs_h, const float* __restrict__ hcs_D, const float* __restrict__ hcs_state,
    const float* __restrict__ hcm_h, const float* __restrict__ hcm_D, const float* __restrict__ hcm_state,
    const float* __restrict__ lp, const float* __restrict__ resd, const float* __restrict__ hcl_D,
    const float* __restrict__ iir,
    unsigned long long kbits,
    float* __restrict__ sfd, float* __restrict__ sfc,
    float* __restrict__ mix0, float* __restrict__ mix1)
{
  int blk = blockIdx.x, tid = threadIdx.x;
  if (blk < 768) {
    int idx = blk * 256 + tid;
    int i = idx / (BATCH * H3);
    int r = idx % (BATCH * H3);
    int b = r / H3, ch = r % H3;
    const float* fs = fir_state + ((size_t)(i * BATCH + b) * H3 + ch) * 2;
    const float* sw = sf_w + ((size_t)i * H3 + ch) * 3;
    sfd[idx] = fs[0] * sw[0] + fs[1] * sw[1] + sf_b[i * H3 + ch];
    if (b == 0) sfc[i * H3 + ch] = sw[2];
  } else if (blk < 1024) {
    int idx = (blk - 768) * 256 + tid;
    int i = idx >> 11;
    int r = idx & 2047;
    int b = r >> 10, c = r & 1023;
    int kind = (int)((kbits >> (2 * i)) & 3ull);
    if (kind == 0) {
      const float* st = hcs_state + ((size_t)(i * BATCH + b) * H + c) * 6;
      const float* hh = hcs_h + ((size_t)i * H + c) * 7;
      float acc = 0.f;
#pragma unroll
      for (int k = 0; k < 6; k++) acc += st[k] * hh[k];
      mix0[idx] = acc + hcs_D[i * H + c];
      if (b == 0) mix1[i * H + c] = hh[6];
    } else if (kind == 2) {
      const float* ii = iir + ((size_t)(i * BATCH + b) * H + c) * 16;
      const float* lpp = lp + ((size_t)i * H + c) * 16;
      const float* rs = resd + ((size_t)i * H + c) * 16;
      float acc = 0.f, rsum = 0.f;
#pragma unroll
      for (int k = 0; k < 16; k++) { float rv = rs[k]; acc += rv * expf(lpp[k]) * ii[k]; rsum += rv; }
      mix0[idx] = acc;
      if (b == 0) mix1[i * H + c] = rsum + hcl_D[i * H + c];
    }
  } else {
    int w = tid >> 6, lane = tid & 63;
    int widx = (blk - 1024) * 4 + w;
    if (widx < 9 * BATCH * H) {
      int li = widx >> 11;
      int r = widx & 2047;
      int b = r >> 10, c = r & 1023;
      int i = (li >> 1) * 7 + ((li & 1) ? 5 : 1);  // HCM layers 1,5,8,12,15,19,22,26,29
      const float* st = hcm_state + ((size_t)(i * BATCH + b) * H + c) * 127;
      const float* hh = hcm_h + ((size_t)i * H + c) * 128;
      float acc = 0.f;
      int k = lane;
      if (k < 127) acc += st[k] * hh[127 - k];
      k = lane + 64;
      if (k < 127) acc += st[k] * hh[127 - k];
      acc = wredSum(acc);
      if (lane == 0) {
        mix0[(i * BATCH + b) * H + c] = acc;
        if (b == 0) mix1[i * H + c] = hh[0] + hcm_D[i * H + c];
      }
    }
  }
}

// ---------------------------------------------------------------------------
// P / W1: fused rmsnorm + GEMV, wave-per-row, x issued BEFORE weights so the
// norm phase overlaps the weight stream (vmcnt is in-order: x first matters).
// P: 768 blocks (4 rows each of 3072), bias, no act.
// W1: 512 blocks (4 rows each of 2048), no bias, gelu.
// ---------------------------------------------------------------------------
template<int ROWS, bool GELU, bool HASBIAS>
__global__ __launch_bounds__(256) void gemv_norm(
    const float* __restrict__ x, const float* __restrict__ nw,
    const float* __restrict__ W, const float* __restrict__ bias,
    float* __restrict__ out)
{
  __shared__ alignas(16) float xe[BATCH * H];
  __shared__ float red[8];
  int tid = threadIdx.x, lane = tid & 63, w = tid >> 6;

  // ---- issue x loads FIRST (norm depends only on these) ----
  float4 xv0 = ((const float4*)x)[tid];          // batch 0
  float4 xv1 = ((const float4*)x)[tid + 256];    // batch 1
  float4 nv  = ((const float4*)nw)[tid];
  // ---- then weight row loads (stream under norm phase) ----
  int r = blockIdx.x * 4 + w;
  const float4* rowp = (const float4*)(W + (size_t)r * H);
  float4 wv0 = rowp[lane], wv1 = rowp[lane + 64],
         wv2 = rowp[lane + 128], wv3 = rowp[lane + 192];

  float ss0 = dot4(xv0, xv0), ss1 = dot4(xv1, xv1);
  ((float4*)xe)[tid]       = make_float4(xv0.x * nv.x, xv0.y * nv.y, xv0.z * nv.z, xv0.w * nv.w);
  ((float4*)xe)[tid + 256] = make_float4(xv1.x * nv.x, xv1.y * nv.y, xv1.z * nv.z, xv1.w * nv.w);
  ss0 = wredSum(ss0); ss1 = wredSum(ss1);
  if (lane == 0) { red[w] = ss0; red[4 + w] = ss1; }
  __syncthreads();
  float s0 = rsqrtf((red[0] + red[1] + red[2] + red[3]) * (1.0f / H) + EPSF);
  float s1 = rsqrtf((red[4] + red[5] + red[6] + red[7]) * (1.0f / H) + EPSF);

  const float4* x4 = (const float4*)xe;
  float a0 = dot4(wv0, x4[lane])       + dot4(wv1, x4[lane + 64])
           + dot4(wv2, x4[lane + 128]) + dot4(wv3, x4[lane + 192]);
  float a1 = dot4(wv0, x4[lane + 256]) + dot4(wv1, x4[lane + 320])
           + dot4(wv2, x4[lane + 384]) + dot4(wv3, x4[lane + 448]);
  a0 = wredSum(a0); a1 = wredSum(a1);
  if (lane == 0) {
    float b0 = HASBIAS ? bias[r] : 0.f;
    float v0 = a0 * s0 + b0, v1 = a1 * s1 + b0;
    if (GELU) { v0 = gelu_t(v0); v1 = gelu_t(v1); }
    out[r] = v0;
    out[ROWS + r] = v1;
  }
}

// ---------------------------------------------------------------------------
// mixer (redundant per block, L2-broadcast inputs) + out_W GEMV + residual
// 256 blocks x 4 rows; mixer loads issued first, weights second.
// ---------------------------------------------------------------------------
__global__ __launch_bounds__(256) void mix_out_kernel(
    int kind,
    const float* __restrict__ z, const float* __restrict__ sfdL, const float* __restrict__ sfcL,
    const float* __restrict__ mix0L, const float* __restrict__ mix1L,
    const float* __restrict__ attP,
    const float* __restrict__ oW, const float* __restrict__ ob,
    const float* __restrict__ x_in, float* __restrict__ x_out)
{
  __shared__ alignas(16) float ys[BATCH * H];
  int tid = threadIdx.x, lane = tid & 63, w = tid >> 6;
  int r = blockIdx.x * 4 + w;

  if (kind < 3) {
    // mixer input loads (mostly cache-resident) — issued before weights
    float x2v[8], x1v[8], vvv[8];
#pragma unroll
    for (int it = 0; it < 8; it++) {
      int e = tid + it * 256;
      int b = e >> 10, c = e & 1023;
      int n = c >> 6, d = c & 63;
      int base = n * 192 + d;
      x2v[it] = sfcL[base] * z[b * H3 + base] + sfdL[b * H3 + base];
      x1v[it] = sfcL[base + 64] * z[b * H3 + base + 64] + sfdL[b * H3 + base + 64];
      vvv[it] = sfcL[base + 128] * z[b * H3 + base + 128] + sfdL[b * H3 + base + 128];
    }
    const float4* rowp = (const float4*)(oW + (size_t)r * H);
    float4 wv0 = rowp[lane], wv1 = rowp[lane + 64],
           wv2 = rowp[lane + 128], wv3 = rowp[lane + 192];
#pragma unroll
    for (int it = 0; it < 8; it++) {
      int e = tid + it * 256;
      int b = e >> 10, c = e & 1023;
      float t = x1v[it] * vvv[it];
      ys[e] = (mix1L[c] * t + mix0L[b * H + c]) * x2v[it];
    }
    __syncthreads();
    const float4* y4 = (const float4*)ys;
    float a0 = dot4(wv0, y4[lane])       + dot4(wv1, y4[lane + 64])
             + dot4(wv2, y4[lane + 128]) + dot4(wv3, y4[lane + 192]);
    float a1 = dot4(wv0, y4[lane + 256]) + dot4(wv1, y4[lane + 320])
             + dot4(wv2, y4[lane + 384]) + dot4(wv3, y4[lane + 448]);
    a0 = wredSum(a0); a1 = wredSum(a1);
    if (lane == 0) {
      x_out[r]     = a0 + ob[r] + x_in[r];
      x_out[H + r] = a1 + ob[r] + x_in[H + r];
    }
  } else {
    const float4* rowp = (const float4*)(oW + (size_t)r * H);
    float4 wv0 = rowp[lane], wv1 = rowp[lane + 64],
           wv2 = rowp[lane + 128], wv3 = rowp[lane + 192];
#pragma unroll
    for (int it = 0; it < 8; it++) {
      int e = tid + it * 256;
      int b = e >> 10, c = e & 1023;
      int n = c >> 6, d = c & 63;
      float M = -1e30f;
#pragma unroll
      for (int sp = 0; sp < 8; sp++) M = fmaxf(M, attP[((sp * BATCH + b) * NHEADS + n) * 66 + 64]);
      float Ls = 0.f, num = 0.f;
#pragma unroll
      for (int sp = 0; sp < 8; sp++) {
        const float* P = attP + ((sp * BATCH + b) * NHEADS + n) * 66;
        float wgt = expf(P[64] - M);
        Ls += wgt * P[65];
        num += wgt * P[d];
      }
      ys[e] = num / Ls;
    }
    __syncthreads();
    const float4* y4 = (const float4*)ys;
    float a0 = dot4(wv0, y4[lane])       + dot4(wv1, y4[lane + 64])
             + dot4(wv2, y4[lane + 128]) + dot4(wv3, y4[lane + 192]);
    float a1 = dot4(wv0, y4[lane + 256]) + dot4(wv1, y4[lane + 320])
             + dot4(wv2, y4[lane + 384]) + dot4(wv3, y4[lane + 448]);
    a0 = wredSum(a0); a1 = wredSum(a1);
    if (lane == 0) {
      x_out[r]     = a0 + ob[r] + x_in[r];
      x_out[H + r] = a1 + ob[r] + x_in[H + r];
    }
  }
}

// ---------------------------------------------------------------------------
// W2 GEMV + residual. 256 blocks x 4 rows (row len FF). h staged in LDS,
// h loads issued before weights.
// ---------------------------------------------------------------------------
__global__ __launch_bounds__(256) void gemv_mlp2(
    const float* __restrict__ h, const float* __restrict__ W2,
    const float* __restrict__ xM, float* __restrict__ x_out)
{
  __shared__ alignas(16) float hs[BATCH * FF];
  int tid = threadIdx.x, lane = tid & 63, w = tid >> 6;
  // h loads first
  float4 h0 = ((const float4*)h)[tid];
  float4 h1 = ((const float4*)h)[tid + 256];
  float4 h2 = ((const float4*)h)[tid + 512];
  float4 h3 = ((const float4*)h)[tid + 768];
  // weights second
  int r = blockIdx.x * 4 + w;
  const float4* rowp = (const float4*)(W2 + (size_t)r * FF);
  float4 wv[8];
#pragma unroll
  for (int j = 0; j < 8; j++) wv[j] = rowp[lane + 64 * j];

  ((float4*)hs)[tid]       = h0;
  ((float4*)hs)[tid + 256] = h1;
  ((float4*)hs)[tid + 512] = h2;
  ((float4*)hs)[tid + 768] = h3;
  __syncthreads();

  const float4* h4 = (const float4*)hs;
  float a0 = 0.f, a1 = 0.f;
#pragma unroll
  for (int j = 0; j < 8; j++) {
    a0 += dot4(wv[j], h4[lane + 64 * j]);
    a1 += dot4(wv[j], h4[lane + 64 * j + 512]);
  }
  a0 = wredSum(a0); a1 = wredSum(a1);
  if (lane == 0) {
    x_out[r]     = a0 + xM[r];
    x_out[H + r] = a1 + xM[H + r];
  }
}

// ---------------------------------------------------------------------------
// flash-decode attention partials (r1-verified): 8 splits x 16 heads x 2 batch
// ---------------------------------------------------------------------------
__global__ __launch_bounds__(256) void attn_kernel(
    const float* __restrict__ z, const int* __restrict__ posp,
    const float* __restrict__ kc, const float* __restrict__ vc,
    const float* __restrict__ cosT, const float* __restrict__ sinT,
    float* __restrict__ P)
{
  int sp = blockIdx.x & 7, n = (blockIdx.x >> 3) & 15, b = blockIdx.x >> 7;
  int pos = *posp;
  __shared__ alignas(16) float q_s[HDIM], k_s[HDIM], v_s[HDIM];
  __shared__ float eg[256];
  __shared__ float redA[4];
  __shared__ alignas(16) float osum[4][HDIM];
  int tid = threadIdx.x, lane = tid & 63, w = tid >> 6;

  if (tid < 64) {
    int d = tid, j = d & 31;
    float cs = cosT[pos * 32 + j], sn = sinT[pos * 32 + j];
    float qv = z[b * H3 + n * 64 + d];
    float qo = z[b * H3 + n * 64 + ((d + 32) & 63)];
    q_s[d] = ((d < 32) ? (qv * cs - qo * sn) : (qv * cs + qo * sn)) * 0.125f;
    float kv = z[b * H3 + 1024 + n * 64 + d];
    float ko = z[b * H3 + 1024 + n * 64 + ((d + 32) & 63)];
    k_s[d] = (d < 32) ? (kv * cs - ko * sn) : (kv * cs + ko * sn);
    v_s[d] = z[b * H3 + 2048 + n * 64 + d];
  }
  __syncthreads();

  int s = sp * 256 + tid;
  float logit = -1e30f;
  if (s <= pos) {
    const float4* k4 = (s == pos) ? (const float4*)k_s
                                  : (const float4*)(kc + (((size_t)b * SEQ + s) * NHEADS + n) * HDIM);
    const float4* q4 = (const float4*)q_s;
    float acc = 0.f;
#pragma unroll
    for (int j = 0; j < 16; j++) acc += dot4(k4[j], q4[j]);
    logit = acc;
  }
  float m = wredMax(logit);
  if (lane == 0) redA[w] = m;
  __syncthreads();
  m = fmaxf(fmaxf(redA[0], redA[1]), fmaxf(redA[2], redA[3]));
  float e = (s <= pos) ? expf(logit - m) : 0.f;
  eg[tid] = e;
  float ps = wredSum(e);
  __syncthreads();
  if (lane == 0) redA[w] = ps;
  __syncthreads();
  float lsum = redA[0] + redA[1] + redA[2] + redA[3];

  int dgrp = lane & 15, srow = lane >> 4;
  float4 acc = make_float4(0.f, 0.f, 0.f, 0.f);
#pragma unroll 4
  for (int it = 0; it < 16; it++) {
    int sl = w * 64 + it * 4;
    if (sp * 256 + sl > pos) break;              // uniform within wave
    int sli = sl + srow;
    int ss = sp * 256 + sli;
    float ev = eg[sli];
    const float4* v4 = (ss == pos) ? (const float4*)v_s
                                   : (const float4*)(vc + (((size_t)b * SEQ + ss) * NHEADS + n) * HDIM);
    float4 vv = v4[dgrp];
    acc.x += ev * vv.x; acc.y += ev * vv.y; acc.z += ev * vv.z; acc.w += ev * vv.w;
  }
#pragma unroll
  for (int mm = 16; mm <= 32; mm <<= 1) {
    acc.x += __shfl_xor(acc.x, mm, 64);
    acc.y += __shfl_xor(acc.y, mm, 64);
    acc.z += __shfl_xor(acc.z, mm, 64);
    acc.w += __shfl_xor(acc.w, mm, 64);
  }
  if (srow == 0) ((float4*)osum[w])[dgrp] = acc;
  __syncthreads();
  float* Pp = P + ((size_t)(sp * BATCH + b) * NHEADS + n) * 66;
  if (tid < 64) Pp[tid] = osum[0][tid] + osum[1][tid] + osum[2][tid] + osum[3][tid];
  if (tid == 64) Pp[64] = m;
  if (tid == 65) Pp[65] = lsum;
}

// ---------------------------------------------------------------------------
extern "C" void kernel_launch(void* const* d_in, const int* in_sizes, int n_in,
                              void* d_out, int out_size, void* d_ws, size_t ws_size,
                              hipStream_t stream) {
  (void)in_sizes; (void)n_in; (void)out_size; (void)ws_size;
  const float* x0    = (const float*)d_in[0];
  const int*   posp  = (const int*)d_in[1];
  const float* n1    = (const float*)d_in[2];
  const float* n2    = (const float*)d_in[3];
  const float* pW    = (const float*)d_in[4];
  const float* pb    = (const float*)d_in[5];
  const float* oW    = (const float*)d_in[6];
  const float* ob    = (const float*)d_in[7];
  const float* W1    = (const float*)d_in[8];
  const float* W2    = (const float*)d_in[9];
  const float* sfw   = (const float*)d_in[10];
  const float* sfb   = (const float*)d_in[11];
  const float* hcs_h = (const float*)d_in[12];
  const float* hcs_D = (const float*)d_in[13];
  const float* hcm_h = (const float*)d_in[14];
  const float* hcm_D = (const float*)d_in[15];
  const float* lp    = (const float*)d_in[16];
  const float* resd  = (const float*)d_in[17];
  const float* hclD  = (const float*)d_in[18];
  const float* fir   = (const float*)d_in[19];
  const float* hcsS  = (const float*)d_in[20];
  const float* hcmS  = (const float*)d_in[21];
  const float* iir   = (const float*)d_in[22];
  const float* kc    = (const float*)d_in[23];
  const float* vc    = (const float*)d_in[24];
  const float* cosT  = (const float*)d_in[25];
  const float* sinT  = (const float*)d_in[26];

  float* ws    = (float*)d_ws;
  float* xbuf0 = ws;                 // 2048
  float* xbuf1 = ws + 2048;          // 2048
  float* xM    = ws + 4096;          // 2048
  float* zbuf  = ws + 6144;          // 6144
  float* hbuf  = ws + 12288;         // 4096
  float* attP  = ws + 16384;         // 16896
  float* sfd   = ws + 33280;         // 196608
  float* sfc   = ws + 229888;        // 98304
  float* mix0  = ws + 328192;        // 65536
  float* mix1  = ws + 393728;        // 32768

  static const int KIND[LAYERS] = {0,1,2,3,0,1,2,0,1,2,3,0,1,2,0,1,2,3,0,1,2,0,1,2,3,0,1,2,0,1,2,3};
  unsigned long long kbits = 0ull;
  for (int i = 0; i < LAYERS; i++) kbits |= ((unsigned long long)KIND[i]) << (2 * i);

  prep_kernel<<<5632, 256, 0, stream>>>(sfw, sfb, fir, hcs_h, hcs_D, hcsS,
      hcm_h, hcm_D, hcmS, lp, resd, hclD, iir, kbits, sfd, sfc, mix0, mix1);

  const float* xsrc = x0;
  int att = 0;
  for (int i = 0; i < LAYERS; i++) {
    gemv_norm<H3, false, true><<<H3 / 4, 256, 0, stream>>>(
        xsrc, n1 + i * H, pW + (size_t)i * H3 * H, pb + i * H3, zbuf);
    if (KIND[i] == 3) {
      attn_kernel<<<256, 256, 0, stream>>>(
          zbuf, posp, kc + (size_t)att * BATCH * SEQ * NHEADS * HDIM,
          vc + (size_t)att * BATCH * SEQ * NHEADS * HDIM, cosT, sinT, attP);
      att++;
    }
    mix_out_kernel<<<H / 4, 256, 0, stream>>>(
        KIND[i], zbuf, sfd + (size_t)i * BATCH * H3, sfc + (size_t)i * H3,
        mix0 + (size_t)i * BATCH * H, mix1 + (size_t)i * H, attP,
        oW + (size_t)i * H * H, ob + i * H, xsrc, xM);
    gemv_norm<FF, true, false><<<FF / 4, 256, 0, stream>>>(
        xM, n2 + i * H, W1 + (size_t)i * FF * H, nullptr, hbuf);
    float* xout = (i == LAYERS - 1) ? (float*)d_out : ((i & 1) ? xbuf1 : xbuf0);
    gemv_mlp2<<<H / 4, 256, 0, stream>>>(
        hbuf, W2 + (size_t)i * H * FF, xM, xout);
    xsrc = xout;
  }
}